// Round 4
// baseline (7616.032 us; speedup 1.0000x reference)
//
#include <hip/hip_runtime.h>
#include <hip/hip_bf16.h>
#include <math.h>

// Problem dims
#define B_  64
#define T_  256
#define F_  128
#define H_  8
#define E_  1024   // F*H
#define NH_ 4
#define HD_ 256    // E/NH
#define D_  256

// output element offsets within d_out (element units of the storage dtype)
#define OFF_Y_  0L
#define OFF_FI_ 4194304L
#define OFF_IA_ 4210688L

typedef unsigned short u16;
typedef unsigned int   u32;

__device__ __forceinline__ float bf2f(u16 u) {
  union { u32 u; float f; } x; x.u = ((u32)u) << 16; return x.f;
}
__device__ __forceinline__ u16 f2bf(float f) {
  union { float f; u32 u; } x; x.f = f;
  u32 r = (x.u + 0x7fffu + ((x.u >> 16) & 1u)) >> 16;
  return (u16)r;
}
__device__ __forceinline__ float gelu_exact(float v) {
  return 0.5f * v * (1.f + erff(v * 0.70710678118654752f));
}
__device__ __forceinline__ float sigmoidf_(float v) {
  return 1.f / (1.f + __expf(-v));
}
// dtype-flagged load of a raw input tensor element
__device__ __forceinline__ float ldv(const void* p, long i, bool isf) {
  return isf ? ((const float*)p)[i] : bf2f(((const u16*)p)[i]);
}
// dtype-flagged store to an OUTPUT tensor element
__device__ __forceinline__ void stv(void* p, long i, float v, bool isf) {
  if (isf) ((float*)p)[i] = v;
  else ((u16*)p)[i] = f2bf(v);
}

// ---------------------------------------------------------------------------
// dtype detector: sample 512 u16 of x. bf16 storage -> ~all sane exponents;
// f32 storage -> ~58% (mantissa halves are random). flag: 0 = bf16, 1 = f32.
// ---------------------------------------------------------------------------
__global__ void detect_dtype(const u16* __restrict__ x, u32* __restrict__ flag) {
  if (threadIdx.x == 0 && blockIdx.x == 0) {
    int good = 0;
    for (int i = 0; i < 512; ++i) {
      u16 v = x[i];
      int e = (v >> 7) & 0xFF;
      if (v == 0 || (e >= 100 && e <= 140)) ++good;
    }
    *flag = (good >= 450) ? 0u : 1u;
  }
}

// ---------------------------------------------------------------------------
// K1: input-attention MLP. Writes XG (internal bf16), IA + FI into d_out.
// grid = B*T, block = 128
// ---------------------------------------------------------------------------
__global__ __launch_bounds__(128)
void input_mlp2(const void* __restrict__ x,
                const void* __restrict__ w1, const void* __restrict__ b1,
                const void* __restrict__ w2, const void* __restrict__ b2,
                const u32* __restrict__ flag,
                u16* __restrict__ xg, void* __restrict__ dout) {
  const bool isf = (*flag != 0);
  const long row = blockIdx.x;
  const int tid = threadIdx.x;
  __shared__ float xr[F_];
  __shared__ float hid[32];
  __shared__ float red[2];
  float xv = ldv(x, row * F_ + tid, isf);
  xr[tid] = xv;
  __syncthreads();
  if (tid < 32) {
    float s = ldv(b1, tid, isf);
    for (int f = 0; f < F_; ++f) s += xr[f] * ldv(w1, f * 32 + tid, isf);
    hid[tid] = gelu_exact(s);
  }
  __syncthreads();
  float s = ldv(b2, tid, isf);
  #pragma unroll 8
  for (int j = 0; j < 32; ++j) s += hid[j] * ldv(w2, j * F_ + tid, isf);
  float ia = sigmoidf_(s);
  stv(dout, OFF_IA_ + row * F_ + tid, ia, isf);
  xg[row * F_ + tid] = f2bf(ia * xv);
  float v = ia;
  for (int o = 32; o > 0; o >>= 1) v += __shfl_down(v, o);
  if ((tid & 63) == 0) red[tid >> 6] = v;
  __syncthreads();
  if (tid == 0) stv(dout, OFF_FI_ + row, red[0] + red[1], isf);
}

// ---------------------------------------------------------------------------
// K2: bank of F GRUs (input 1, hidden 8). grid=F, block=64 (=batch)
// ---------------------------------------------------------------------------
__global__ __launch_bounds__(64, 1)
void gru_scan2(const u16* __restrict__ xg, const void* __restrict__ W_ih,
               const void* __restrict__ W_hh, const void* __restrict__ b_ih,
               const void* __restrict__ b_hh, const u32* __restrict__ flag,
               u16* __restrict__ gruo) {
  const bool isf = (*flag != 0);
  const int f = blockIdx.x, b = threadIdx.x;
  float wih[24], whh[24][8], brz[16], bin_[8], bhn[8];
  #pragma unroll
  for (int g = 0; g < 24; ++g) wih[g] = ldv(W_ih, f * 24 + g, isf);
  #pragma unroll
  for (int g = 0; g < 24; ++g) {
    #pragma unroll
    for (int j = 0; j < 8; ++j) whh[g][j] = ldv(W_hh, f * 192 + g * 8 + j, isf);
  }
  #pragma unroll
  for (int g = 0; g < 16; ++g) brz[g] = ldv(b_ih, f * 24 + g, isf) + ldv(b_hh, f * 24 + g, isf);
  #pragma unroll
  for (int j = 0; j < 8; ++j) {
    bin_[j] = ldv(b_ih, f * 24 + 16 + j, isf);
    bhn[j]  = ldv(b_hh, f * 24 + 16 + j, isf);
  }
  float h[8];
  #pragma unroll
  for (int j = 0; j < 8; ++j) h[j] = 0.f;
  const u16* xp = xg + (long)b * T_ * F_ + f;
  u16* op = gruo + (long)b * T_ * E_ + f * 8;
  float xv = bf2f(xp[0]);
  for (int t = 0; t < T_; ++t) {
    float xn = (t + 1 < T_) ? bf2f(xp[(t + 1) * F_]) : 0.f;
    float gh[24];
    #pragma unroll
    for (int g = 0; g < 24; ++g) {
      float s = h[0] * whh[g][0];
      #pragma unroll
      for (int j = 1; j < 8; ++j) s += h[j] * whh[g][j];
      gh[g] = s;
    }
    #pragma unroll
    for (int j = 0; j < 8; ++j) {
      float r = sigmoidf_(xv * wih[j]      + gh[j]      + brz[j]);
      float z = sigmoidf_(xv * wih[8 + j]  + gh[8 + j]  + brz[8 + j]);
      float a = xv * wih[16 + j] + bin_[j] + r * (gh[16 + j] + bhn[j]);
      float e = __expf(2.f * a);
      float n = 1.f - 2.f / (e + 1.f);   // tanh(a)
      h[j] = (1.f - z) * n + z * h[j];
    }
    uint4 pk;
    pk.x = (u32)f2bf(h[0]) | ((u32)f2bf(h[1]) << 16);
    pk.y = (u32)f2bf(h[2]) | ((u32)f2bf(h[3]) << 16);
    pk.z = (u32)f2bf(h[4]) | ((u32)f2bf(h[5]) << 16);
    pk.w = (u32)f2bf(h[6]) | ((u32)f2bf(h[7]) << 16);
    *(uint4*)(op + (long)t * E_) = pk;
    xv = xn;
  }
}

// ---------------------------------------------------------------------------
// Dumb GEMM: C[m][ccol0+n] = epi( sum_k A[m][k] * W[k][wcol0+n] + bias[bcol0+n] )
// A: bf16 intermediate [M][lda]. W/bias: RAW input (dtype-flagged), row-major.
// Block: 256 threads = 256 consecutive n; 8 m-rows per block (A staged in LDS).
// grid = (M/8, N/256). EPI: 0=bias, 1=bias+gelu, 2=bias+resid
// COUT: C is the final output y -> dtype-flagged store; else internal bf16.
// ---------------------------------------------------------------------------
template <int EPI, int COUT>
__global__ __launch_bounds__(256)
void dumb_gemm(const u16* __restrict__ A, int lda,
               const void* __restrict__ W, int ldw, int wcol0,
               const void* __restrict__ bias, int bcol0,
               const u16* __restrict__ resid, int ldr,
               void* __restrict__ C, int ldc, int ccol0,
               int K, const u32* __restrict__ flag) {
  const bool isf = (*flag != 0);
  const int tid = threadIdx.x;
  const int m0 = blockIdx.x * 8;
  const int n  = blockIdx.y * 256 + tid;
  __shared__ u16 As[8 * 1024];
  for (int i = tid; i < 8 * K; i += 256)
    As[i] = A[(long)(m0 + i / K) * lda + (i % K)];
  __syncthreads();
  float acc[8];
  #pragma unroll
  for (int r = 0; r < 8; ++r) acc[r] = 0.f;
  for (int kk = 0; kk < K; ++kk) {
    const float w = ldv(W, (long)kk * ldw + wcol0 + n, isf);
    #pragma unroll
    for (int r = 0; r < 8; ++r) acc[r] += bf2f(As[r * K + kk]) * w;
  }
  const float bv = ldv(bias, bcol0 + n, isf);
  #pragma unroll
  for (int r = 0; r < 8; ++r) {
    float v = acc[r] + bv;
    if (EPI == 1) v = gelu_exact(v);
    if (EPI == 2) v += bf2f(resid[(long)(m0 + r) * ldr + n]);
    const long idx = (long)(m0 + r) * ldc + ccol0 + n;
    if (COUT) stv(C, idx, v, isf);
    else ((u16*)C)[idx] = f2bf(v);
  }
}

// ---------------------------------------------------------------------------
// Dumb attention for one head h: per block (t = blockIdx.x, b = blockIdx.y):
// scores -> softmax (LDS) -> ctx row. Q/K/V are per-head [B,T,HD] bf16.
// ---------------------------------------------------------------------------
__global__ __launch_bounds__(256)
void dumb_attn(const u16* __restrict__ Qh, const u16* __restrict__ Kh,
               const u16* __restrict__ Vh, u16* __restrict__ ctx, int h) {
  const int t = blockIdx.x, b = blockIdx.y, tid = threadIdx.x;
  __shared__ float qs[HD_];
  __shared__ float red[256];
  __shared__ float p[256];
  const long rowq = ((long)b * T_ + t) * HD_;
  qs[tid] = bf2f(Qh[rowq + tid]);
  __syncthreads();
  const long rowk = ((long)b * T_ + tid) * HD_;
  float sc = 0.f;
  for (int d0 = 0; d0 < HD_; d0 += 8) {
    uint4 v = *(const uint4*)(Kh + rowk + d0);
    const u16* pv = (const u16*)&v;
    #pragma unroll
    for (int j = 0; j < 8; ++j) sc += qs[d0 + j] * bf2f(pv[j]);
  }
  sc *= 0.0625f;  // 1/sqrt(HD)
  red[tid] = sc;
  __syncthreads();
  for (int o = 128; o > 0; o >>= 1) {
    if (tid < o) red[tid] = fmaxf(red[tid], red[tid + o]);
    __syncthreads();
  }
  const float mx = red[0];
  __syncthreads();
  const float e = __expf(sc - mx);
  red[tid] = e;
  __syncthreads();
  for (int o = 128; o > 0; o >>= 1) {
    if (tid < o) red[tid] += red[tid + o];
    __syncthreads();
  }
  const float inv = 1.f / red[0];
  p[tid] = e * inv;
  __syncthreads();
  float acc = 0.f;
  for (int s = 0; s < T_; ++s)
    acc += p[s] * bf2f(Vh[((long)b * T_ + s) * HD_ + tid]);
  ctx[((long)b * T_ + t) * E_ + h * HD_ + tid] = f2bf(acc);
}

// ---------------------------------------------------------------------------
extern "C" void kernel_launch(void* const* d_in, const int* in_sizes, int n_in,
                              void* d_out, int out_size, void* d_ws, size_t ws_size,
                              hipStream_t stream) {
  (void)in_sizes; (void)n_in; (void)out_size; (void)ws_size;
  char* ws = (char*)d_ws;
  u32* FLAG = (u32*)ws;
  // ws layout (bytes), peak ~92.3MB
  u16* CTX  = (u16*)(ws + 4096);        // [B,T,E] 33.55MB   (XG overlays start)
  u16* XG   = CTX;                      // [B,T,F] 4.19MB, dead before CTX written
  u16* GRUO = (u16*)(ws + 33558528);    // [B,T,E] 33.55MB
  u16* Qh   = (u16*)(ws + 67112960);    // [B,T,HD] 8.39MB
  u16* Kh   = (u16*)(ws + 75501568);    // [B,T,HD] 8.39MB
  u16* Vh   = (u16*)(ws + 83890176);    // [B,T,HD] 8.39MB -> ends 92,278,784
  u16* MHA  = GRUO;                     // overlay (GRUO dead after in_proj passes)
  u16* H1   = Qh;                       // overlay (Qh dead after attention)
  u16* FFH  = Kh;                       // overlay, spans Kh+Vh (16.78MB)

  detect_dtype<<<1, 64, 0, stream>>>((const u16*)d_in[0], FLAG);
  input_mlp2<<<B_ * T_, 128, 0, stream>>>(d_in[0], d_in[1], d_in[2], d_in[3], d_in[4],
                                          FLAG, XG, d_out);
  gru_scan2<<<F_, 64, 0, stream>>>(XG, d_in[5], d_in[6], d_in[7], d_in[8], FLAG, GRUO);

  for (int h = 0; h < NH_; ++h) {
    dumb_gemm<0, 0><<<dim3(2048, 1), 256, 0, stream>>>(GRUO, 1024, d_in[9], 3072, h * 256,
        d_in[10], h * 256, nullptr, 0, Qh, 256, 0, 1024, FLAG);
    dumb_gemm<0, 0><<<dim3(2048, 1), 256, 0, stream>>>(GRUO, 1024, d_in[9], 3072, 1024 + h * 256,
        d_in[10], 1024 + h * 256, nullptr, 0, Kh, 256, 0, 1024, FLAG);
    dumb_gemm<0, 0><<<dim3(2048, 1), 256, 0, stream>>>(GRUO, 1024, d_in[9], 3072, 2048 + h * 256,
        d_in[10], 2048 + h * 256, nullptr, 0, Vh, 256, 0, 1024, FLAG);
    dumb_attn<<<dim3(T_, B_), 256, 0, stream>>>(Qh, Kh, Vh, CTX, h);
  }
  // mha = ctx @ mha_out_w + b
  dumb_gemm<0, 0><<<dim3(2048, 4), 256, 0, stream>>>(CTX, 1024, d_in[11], 1024, 0,
      d_in[12], 0, nullptr, 0, MHA, 1024, 0, 1024, FLAG);
  // h1 = mha @ outp_w + b
  dumb_gemm<0, 0><<<dim3(2048, 1), 256, 0, stream>>>(MHA, 1024, d_in[13], 256, 0,
      d_in[14], 0, nullptr, 0, H1, 256, 0, 1024, FLAG);
  // ffh = gelu(h1 @ ffn_w1 + b)
  dumb_gemm<1, 0><<<dim3(2048, 2), 256, 0, stream>>>(H1, 256, d_in[15], 512, 0,
      d_in[16], 0, nullptr, 0, FFH, 512, 0, 256, FLAG);
  // y = h1 + ffh @ ffn_w2 + b  -> final OUTPUT, dtype-flagged
  dumb_gemm<2, 1><<<dim3(2048, 1), 256, 0, stream>>>(FFH, 512, d_in[17], 256, 0,
      d_in[18], 0, H1, 256, d_out, 256, 0, 512, FLAG);
}

// Round 5
// 1009.209 us; speedup vs baseline: 7.5465x; 7.5465x over previous
//
#include <hip/hip_runtime.h>
#include <hip/hip_bf16.h>
#include <math.h>

// Problem dims
#define B_  64
#define T_  256
#define F_  128
#define H_  8
#define E_  1024   // F*H
#define NH_ 4
#define HD_ 256    // E/NH
#define D_  256

// output element offsets within d_out (element units of the storage dtype)
#define OFF_Y_  0L
#define OFF_FI_ 4194304L
#define OFF_IA_ 4210688L

typedef unsigned short u16;
typedef unsigned int   u32;
typedef short bf16x8 __attribute__((ext_vector_type(8)));
typedef float f32x4  __attribute__((ext_vector_type(4)));

__device__ __forceinline__ float bf2f(u16 u) {
  union { u32 u; float f; } x; x.u = ((u32)u) << 16; return x.f;
}
__device__ __forceinline__ u16 f2bf(float f) {
  union { float f; u32 u; } x; x.f = f;
  u32 r = (x.u + 0x7fffu + ((x.u >> 16) & 1u)) >> 16;
  return (u16)r;
}
__device__ __forceinline__ float gelu_exact(float v) {
  return 0.5f * v * (1.f + erff(v * 0.70710678118654752f));
}
__device__ __forceinline__ float sigmoidf_(float v) {
  return 1.f / (1.f + __expf(-v));
}
__device__ __forceinline__ float ldv(const void* p, long i, bool isf) {
  return isf ? ((const float*)p)[i] : bf2f(((const u16*)p)[i]);
}
__device__ __forceinline__ void stv(void* p, long i, float v, bool isf) {
  if (isf) ((float*)p)[i] = v;
  else ((u16*)p)[i] = f2bf(v);
}

// ---------------------------------------------------------------------------
// dtype detector (flag: 0 = bf16 storage, 1 = f32 storage)
// ---------------------------------------------------------------------------
__global__ void detect_dtype(const u16* __restrict__ x, u32* __restrict__ flag) {
  if (threadIdx.x == 0 && blockIdx.x == 0) {
    int good = 0;
    for (int i = 0; i < 512; ++i) {
      u16 v = x[i];
      int e = (v >> 7) & 0xFF;
      if (v == 0 || (e >= 100 && e <= 140)) ++good;
    }
    *flag = (good >= 450) ? 0u : 1u;
  }
}

// convert a small raw tensor (f32 or bf16) to bf16
__global__ __launch_bounds__(256)
void convert_in(const void* __restrict__ src, u16* __restrict__ dst, int n,
                const u32* __restrict__ flag) {
  const bool isf = (*flag != 0);
  int i = blockIdx.x * 256 + threadIdx.x;
  if (i < n) dst[i] = isf ? f2bf(((const float*)src)[i]) : ((const u16*)src)[i];
}

// fused transpose + convert: out[c][r] (bf16) = in[r][c] (raw). dims %32 == 0
__global__ void transpose_cvt(const void* __restrict__ in, u16* __restrict__ out,
                              int R, int C, const u32* __restrict__ flag) {
  const bool isf = (*flag != 0);
  __shared__ float t[32][33];
  const int c0 = blockIdx.x * 32, r0 = blockIdx.y * 32;
  const int tx = threadIdx.x, ty = threadIdx.y;
  for (int i = ty; i < 32; i += 8)
    t[i][tx] = ldv(in, (long)(r0 + i) * C + c0 + tx, isf);
  __syncthreads();
  for (int i = ty; i < 32; i += 8)
    out[(long)(c0 + i) * R + r0 + tx] = f2bf(t[tx][i]);
}

// ---------------------------------------------------------------------------
// K1: input-attention MLP (unchanged from passing round 4)
// ---------------------------------------------------------------------------
__global__ __launch_bounds__(128)
void input_mlp2(const void* __restrict__ x,
                const void* __restrict__ w1, const void* __restrict__ b1,
                const void* __restrict__ w2, const void* __restrict__ b2,
                const u32* __restrict__ flag,
                u16* __restrict__ xg, void* __restrict__ dout) {
  const bool isf = (*flag != 0);
  const long row = blockIdx.x;
  const int tid = threadIdx.x;
  __shared__ float xr[F_];
  __shared__ float hid[32];
  __shared__ float red[2];
  float xv = ldv(x, row * F_ + tid, isf);
  xr[tid] = xv;
  __syncthreads();
  if (tid < 32) {
    float s = ldv(b1, tid, isf);
    for (int f = 0; f < F_; ++f) s += xr[f] * ldv(w1, f * 32 + tid, isf);
    hid[tid] = gelu_exact(s);
  }
  __syncthreads();
  float s = ldv(b2, tid, isf);
  #pragma unroll 8
  for (int j = 0; j < 32; ++j) s += hid[j] * ldv(w2, j * F_ + tid, isf);
  float ia = sigmoidf_(s);
  stv(dout, OFF_IA_ + row * F_ + tid, ia, isf);
  xg[row * F_ + tid] = f2bf(ia * xv);
  float v = ia;
  for (int o = 32; o > 0; o >>= 1) v += __shfl_down(v, o);
  if ((tid & 63) == 0) red[tid >> 6] = v;
  __syncthreads();
  if (tid == 0) stv(dout, OFF_FI_ + row, red[0] + red[1], isf);
}

// ---------------------------------------------------------------------------
// K2: GRU bank (unchanged from passing round 4)
// ---------------------------------------------------------------------------
__global__ __launch_bounds__(64, 1)
void gru_scan2(const u16* __restrict__ xg, const void* __restrict__ W_ih,
               const void* __restrict__ W_hh, const void* __restrict__ b_ih,
               const void* __restrict__ b_hh, const u32* __restrict__ flag,
               u16* __restrict__ gruo) {
  const bool isf = (*flag != 0);
  const int f = blockIdx.x, b = threadIdx.x;
  float wih[24], whh[24][8], brz[16], bin_[8], bhn[8];
  #pragma unroll
  for (int g = 0; g < 24; ++g) wih[g] = ldv(W_ih, f * 24 + g, isf);
  #pragma unroll
  for (int g = 0; g < 24; ++g) {
    #pragma unroll
    for (int j = 0; j < 8; ++j) whh[g][j] = ldv(W_hh, f * 192 + g * 8 + j, isf);
  }
  #pragma unroll
  for (int g = 0; g < 16; ++g) brz[g] = ldv(b_ih, f * 24 + g, isf) + ldv(b_hh, f * 24 + g, isf);
  #pragma unroll
  for (int j = 0; j < 8; ++j) {
    bin_[j] = ldv(b_ih, f * 24 + 16 + j, isf);
    bhn[j]  = ldv(b_hh, f * 24 + 16 + j, isf);
  }
  float h[8];
  #pragma unroll
  for (int j = 0; j < 8; ++j) h[j] = 0.f;
  const u16* xp = xg + (long)b * T_ * F_ + f;
  u16* op = gruo + (long)b * T_ * E_ + f * 8;
  float xv = bf2f(xp[0]);
  for (int t = 0; t < T_; ++t) {
    float xn = (t + 1 < T_) ? bf2f(xp[(t + 1) * F_]) : 0.f;
    float gh[24];
    #pragma unroll
    for (int g = 0; g < 24; ++g) {
      float s = h[0] * whh[g][0];
      #pragma unroll
      for (int j = 1; j < 8; ++j) s += h[j] * whh[g][j];
      gh[g] = s;
    }
    #pragma unroll
    for (int j = 0; j < 8; ++j) {
      float r = sigmoidf_(xv * wih[j]      + gh[j]      + brz[j]);
      float z = sigmoidf_(xv * wih[8 + j]  + gh[8 + j]  + brz[8 + j]);
      float a = xv * wih[16 + j] + bin_[j] + r * (gh[16 + j] + bhn[j]);
      float e = __expf(2.f * a);
      float n = 1.f - 2.f / (e + 1.f);   // tanh(a)
      h[j] = (1.f - z) * n + z * h[j];
    }
    uint4 pk;
    pk.x = (u32)f2bf(h[0]) | ((u32)f2bf(h[1]) << 16);
    pk.y = (u32)f2bf(h[2]) | ((u32)f2bf(h[3]) << 16);
    pk.z = (u32)f2bf(h[4]) | ((u32)f2bf(h[5]) << 16);
    pk.w = (u32)f2bf(h[6]) | ((u32)f2bf(h[7]) << 16);
    *(uint4*)(op + (long)t * E_) = pk;
    xv = xn;
  }
}

// ---------------------------------------------------------------------------
// bt-form MFMA GEMM: C[m][n] = sum_k A[m][k]*B[n][k]  (+epilogues)
// 128x128 tile, BK=32, 4 waves (2x2), reg-staged LDS.
// EPI: 0=none, 1=+bias, 2=+bias+gelu, 3=+bias+resid,
//      4=+bias, write V transposed: VT[((row>>8)*4+(col>>8))*256+(col&255)][row&255]
// COUT: 1 -> final y output, dtype-flagged f32/bf16 store
// ---------------------------------------------------------------------------
template <int EPI, int COUT>
__global__ __launch_bounds__(256)
void gemm_bt(const u16* __restrict__ A, int lda, long abs_,
             const u16* __restrict__ Bp, int ldb, long bbs_,
             void* __restrict__ Cg, int ldc, long cbs_o, long cbs_i, int cmod,
             const u16* __restrict__ bias, const u16* __restrict__ resid,
             int K, int nbm, const u32* __restrict__ flag) {
  const bool isf = (*flag != 0);
  const int z = blockIdx.y;
  const int bm = blockIdx.x % nbm, bn = blockIdx.x / nbm;
  const int w = threadIdx.x >> 6, lane = threadIdx.x & 63;
  A += (long)z * abs_;
  Bp += (long)z * bbs_;
  const long coff = (long)(z / cmod) * cbs_o + (long)(z % cmod) * cbs_i;
  __shared__ __align__(16) u16 As[128 * 32];
  __shared__ __align__(16) u16 Bs[128 * 32];
  const long m0 = (long)bm * 128, n0 = (long)bn * 128;
  const int wm = w >> 1, wn = w & 1;
  const int rr = lane >> 2, cc = lane & 3;
  const int r0 = w * 32 + rr, r1 = r0 + 16;
  const u16* pa0 = A + (m0 + r0) * (long)lda + cc * 8;
  const u16* pa1 = A + (m0 + r1) * (long)lda + cc * 8;
  const u16* pb0 = Bp + (n0 + r0) * (long)ldb + cc * 8;
  const u16* pb1 = Bp + (n0 + r1) * (long)ldb + cc * 8;
  u16* sa0 = &As[r0 * 32 + cc * 8]; u16* sa1 = &As[r1 * 32 + cc * 8];
  u16* sb0 = &Bs[r0 * 32 + cc * 8]; u16* sb1 = &Bs[r1 * 32 + cc * 8];
  f32x4 acc[4][4] = {};
  const int nk = K >> 5;
  const int lr = lane & 15, lk = (lane >> 4) * 8;
  for (int kt = 0; kt < nk; ++kt) {
    const int k0 = kt << 5;
    uint4 va0 = *(const uint4*)(pa0 + k0);
    uint4 va1 = *(const uint4*)(pa1 + k0);
    uint4 vb0 = *(const uint4*)(pb0 + k0);
    uint4 vb1 = *(const uint4*)(pb1 + k0);
    __syncthreads();
    *(uint4*)sa0 = va0; *(uint4*)sa1 = va1;
    *(uint4*)sb0 = vb0; *(uint4*)sb1 = vb1;
    __syncthreads();
    bf16x8 af[4], bfv[4];
    #pragma unroll
    for (int i = 0; i < 4; ++i)
      af[i] = *(const bf16x8*)&As[(wm * 64 + i * 16 + lr) * 32 + lk];
    #pragma unroll
    for (int i = 0; i < 4; ++i)
      bfv[i] = *(const bf16x8*)&Bs[(wn * 64 + i * 16 + lr) * 32 + lk];
    #pragma unroll
    for (int i = 0; i < 4; ++i) {
      #pragma unroll
      for (int j = 0; j < 4; ++j)
        acc[i][j] = __builtin_amdgcn_mfma_f32_16x16x32_bf16(af[i], bfv[j], acc[i][j], 0, 0, 0);
    }
  }
  // epilogue: C/D layout col = lane&15, row = (lane>>4)*4 + q
  const int rq = (lane >> 4) * 4;
  #pragma unroll
  for (int j = 0; j < 4; ++j) {
    const long col = n0 + wn * 64 + j * 16 + lr;
    const float bv = (EPI >= 1) ? bf2f(bias[col]) : 0.f;
    #pragma unroll
    for (int i = 0; i < 4; ++i) {
      const long row0 = m0 + wm * 64 + i * 16 + rq;
      #pragma unroll
      for (int q = 0; q < 4; ++q) {
        const long row = row0 + q;
        float v = acc[i][j][q] + bv;
        if (EPI == 2) v = gelu_exact(v);
        if (EPI == 3) v += bf2f(resid[row * (long)ldc + col]);
        if (EPI == 4) {
          const long idx = (((row >> 8) * 4 + (col >> 8)) * 256 + (col & 255)) * 256 + (row & 255);
          ((u16*)Cg)[idx] = f2bf(v);
        } else if (COUT) {
          stv(Cg, coff + row * (long)ldc + col, v, isf);
        } else {
          ((u16*)Cg)[coff + row * (long)ldc + col] = f2bf(v);
        }
      }
    }
  }
}

// ---------------------------------------------------------------------------
// ATT1: P[z][t][s] = softmax_s(q.k/16). QK layout [B,T,2E] bf16.
// Block: 64 q-rows (4 waves x 16), full 256 k. grid = (T/64, B*NH)
// ---------------------------------------------------------------------------
__global__ __launch_bounds__(256)
void attn_qk_softmax(const u16* __restrict__ qk, u16* __restrict__ P) {
  const int z = blockIdx.y, bb = z >> 2, hh = z & 3;
  const int w = threadIdx.x >> 6, lane = threadIdx.x & 63;
  const long t0 = (long)blockIdx.x * 64;
  __shared__ __align__(16) u16 Qs[64 * 32];
  __shared__ __align__(16) u16 Ks[256 * 32];
  const u16* qb = qk + (long)bb * T_ * 2 * E_ + hh * HD_;
  const u16* kb = qb + E_;
  const int rr = lane >> 2, cc = lane & 3;
  const int lr = lane & 15, lk = (lane >> 4) * 8;
  f32x4 acc[16] = {};
  for (int kt = 0; kt < 8; ++kt) {
    const int k0 = kt * 32;
    uint4 vq = *(const uint4*)(qb + (t0 + w * 16 + rr) * (2L * E_) + k0 + cc * 8);
    uint4 vk[4];
    #pragma unroll
    for (int c = 0; c < 4; ++c)
      vk[c] = *(const uint4*)(kb + (long)(w * 64 + c * 16 + rr) * (2L * E_) + k0 + cc * 8);
    __syncthreads();
    *(uint4*)&Qs[(w * 16 + rr) * 32 + cc * 8] = vq;
    #pragma unroll
    for (int c = 0; c < 4; ++c)
      *(uint4*)&Ks[(w * 64 + c * 16 + rr) * 32 + cc * 8] = vk[c];
    __syncthreads();
    bf16x8 aq = *(const bf16x8*)&Qs[(w * 16 + lr) * 32 + lk];
    #pragma unroll
    for (int nt = 0; nt < 16; ++nt) {
      bf16x8 bk = *(const bf16x8*)&Ks[(nt * 16 + lr) * 32 + lk];
      acc[nt] = __builtin_amdgcn_mfma_f32_16x16x32_bf16(aq, bk, acc[nt], 0, 0, 0);
    }
  }
  u16* Pp = P + (long)z * (T_ * T_);
  #pragma unroll
  for (int q = 0; q < 4; ++q) {
    float mx = -3.4e38f;
    #pragma unroll
    for (int nt = 0; nt < 16; ++nt) mx = fmaxf(mx, acc[nt][q]);
    mx = fmaxf(mx, __shfl_xor(mx, 1));
    mx = fmaxf(mx, __shfl_xor(mx, 2));
    mx = fmaxf(mx, __shfl_xor(mx, 4));
    mx = fmaxf(mx, __shfl_xor(mx, 8));
    float e[16], sum = 0.f;
    #pragma unroll
    for (int nt = 0; nt < 16; ++nt) {
      e[nt] = __expf((acc[nt][q] - mx) * 0.0625f);
      sum += e[nt];
    }
    sum += __shfl_xor(sum, 1);
    sum += __shfl_xor(sum, 2);
    sum += __shfl_xor(sum, 4);
    sum += __shfl_xor(sum, 8);
    const float inv = 1.f / sum;
    const long rowg = t0 + w * 16 + (lane >> 4) * 4 + q;
    #pragma unroll
    for (int nt = 0; nt < 16; ++nt)
      Pp[rowg * T_ + nt * 16 + (lane & 15)] = f2bf(e[nt] * inv);
  }
}

// ---------------------------------------------------------------------------
extern "C" void kernel_launch(void* const* d_in, const int* in_sizes, int n_in,
                              void* d_out, int out_size, void* d_ws, size_t ws_size,
                              hipStream_t stream) {
  (void)in_sizes; (void)n_in; (void)out_size; (void)ws_size;
  char* ws = (char*)d_ws;
  // ws layout (bytes), peak ~151MB (proven safe: round 2 wrote to 165.7MB cleanly)
  u16* BIASA = (u16*)(ws + 0);          // bf16 biases: ipb@0(3072) mhb@3072 opb@4096 fb1@4352 fb2@4864
  u32* FLAG  = (u32*)(ws + 12288);
  u16* wtI   = (u16*)(ws + 65536);      // [3072][1024] 6.29MB
  u16* wtM   = (u16*)(ws + 6356992);    // [1024][1024] 2.10MB
  u16* wtO   = (u16*)(ws + 8454144);    // [256][1024]  0.52MB
  u16* wtF1  = (u16*)(ws + 8978432);    // [512][256]
  u16* wtF2  = (u16*)(ws + 9240576);    // [256][512]   -> ends 9502720
  u16* XG    = (u16*)(ws + 9502720);    // [B,T,F] 4.19MB (dead after gru)
  u16* GRUO  = (u16*)(ws + 16777216);   // [B,T,E] 33.55MB (dead after V gemm)
  u16* Pbuf  = GRUO;                    // [B*NH][T][T] 33.55MB overlay (dead after PV)
  u16* H1    = (u16*)(ws + 16777216);   // [B,T,D] 8.39MB overlay on dead P
  u16* FFH   = (u16*)(ws + 25165824);   // [B,T,2D] 16.78MB overlay on dead P
  u16* QK    = (u16*)(ws + 50331648);   // [B,T,2E] 67.1MB (dead after attn) -> ends 117440512
  u16* CTX   = QK;                      // [B,T,E] 33.55MB overlay on dead QK
  u16* MHA   = (u16*)(ws + 83886080);   // [B,T,E] 33.55MB overlay on dead QK tail
  u16* VT    = (u16*)(ws + 117440512);  // [B*NH][HD][T] 33.55MB -> ends 150994944

  detect_dtype<<<1, 64, 0, stream>>>((const u16*)d_in[0], FLAG);

  // biases -> bf16 arena
  convert_in<<<12, 256, 0, stream>>>(d_in[10], BIASA + 0,    3072, FLAG);
  convert_in<<<4,  256, 0, stream>>>(d_in[12], BIASA + 3072, 1024, FLAG);
  convert_in<<<1,  256, 0, stream>>>(d_in[14], BIASA + 4096, 256,  FLAG);
  convert_in<<<2,  256, 0, stream>>>(d_in[16], BIASA + 4352, 512,  FLAG);
  convert_in<<<1,  256, 0, stream>>>(d_in[18], BIASA + 4864, 256,  FLAG);

  dim3 tb(32, 8);
  // weights: raw [R][C] -> bf16 transposed [C][R]
  transpose_cvt<<<dim3(3072 / 32, 1024 / 32), tb, 0, stream>>>(d_in[9],  wtI,  1024, 3072, FLAG);
  transpose_cvt<<<dim3(1024 / 32, 1024 / 32), tb, 0, stream>>>(d_in[11], wtM,  1024, 1024, FLAG);
  transpose_cvt<<<dim3(256 / 32, 1024 / 32),  tb, 0, stream>>>(d_in[13], wtO,  1024, 256,  FLAG);
  transpose_cvt<<<dim3(512 / 32, 256 / 32),   tb, 0, stream>>>(d_in[15], wtF1, 256,  512,  FLAG);
  transpose_cvt<<<dim3(256 / 32, 512 / 32),   tb, 0, stream>>>(d_in[17], wtF2, 512,  256,  FLAG);

  input_mlp2<<<B_ * T_, 128, 0, stream>>>(d_in[0], d_in[1], d_in[2], d_in[3], d_in[4],
                                          FLAG, XG, d_out);
  gru_scan2<<<F_, 64, 0, stream>>>(XG, d_in[5], d_in[6], d_in[7], d_in[8], FLAG, GRUO);

  // qk = gruo @ Wqk + b   (M=16384, N=2048, K=1024)
  gemm_bt<1, 0><<<dim3(128 * 16, 1), 256, 0, stream>>>(GRUO, 1024, 0, wtI, 1024, 0,
      QK, 2048, 0, 0, 1, BIASA, nullptr, 1024, 128, FLAG);
  // vt = (gruo @ Wv + b)^T per head  (M=16384, N=1024, K=1024) -> VT[z][d][s]
  gemm_bt<4, 0><<<dim3(128 * 8, 1), 256, 0, stream>>>(GRUO, 1024, 0, wtI + 2048 * 1024, 1024, 0,
      VT, 0, 0, 0, 1, BIASA + 2048, nullptr, 1024, 128, FLAG);
  // P = softmax(QK^T/16)  (GRUO dead; P overlays it)
  attn_qk_softmax<<<dim3(T_ / 64, B_ * NH_), 256, 0, stream>>>(QK, Pbuf);
  // ctx = P @ V  (batched z=256: M=256,N=256,K=256) -> CTX [B,T,E] (overlays dead QK)
  gemm_bt<0, 0><<<dim3(2 * 2, B_ * NH_), 256, 0, stream>>>(Pbuf, 256, 65536, VT, 256, 65536,
      CTX, 1024, (long)T_ * E_, 256, 4, nullptr, nullptr, 256, 2, FLAG);
  // mha = ctx @ mha_out_w + b  (M=16384, N=1024, K=1024)
  gemm_bt<1, 0><<<dim3(128 * 8, 1), 256, 0, stream>>>(CTX, 1024, 0, wtM, 1024, 0,
      MHA, 1024, 0, 0, 1, BIASA + 3072, nullptr, 1024, 128, FLAG);
  // h1 = mha @ outp_w + b  (M=16384, N=256, K=1024)  (P dead; H1 overlays)
  gemm_bt<1, 0><<<dim3(128 * 2, 1), 256, 0, stream>>>(MHA, 1024, 0, wtO, 1024, 0,
      H1, 256, 0, 0, 1, BIASA + 4096, nullptr, 1024, 128, FLAG);
  // ffh = gelu(h1 @ ffn_w1 + b)  (M=16384, N=512, K=256)
  gemm_bt<2, 0><<<dim3(128 * 4, 1), 256, 0, stream>>>(H1, 256, 0, wtF1, 256, 0,
      FFH, 512, 0, 0, 1, BIASA + 4352, nullptr, 256, 128, FLAG);
  // y = h1 + ffh @ ffn_w2 + b  (M=16384, N=256, K=512) -> final output (flagged dtype)
  gemm_bt<3, 1><<<dim3(128 * 2, 1), 256, 0, stream>>>(FFH, 512, 0, wtF2, 512, 0,
      d_out, 256, 0, 0, 1, BIASA + 4864, H1, 512, 128, FLAG);
}

// Round 6
// 660.616 us; speedup vs baseline: 11.5287x; 1.5277x over previous
//
#include <hip/hip_runtime.h>
#include <hip/hip_bf16.h>
#include <math.h>

// Problem dims
#define B_  64
#define T_  256
#define F_  128
#define H_  8
#define E_  1024   // F*H
#define NH_ 4
#define HD_ 256    // E/NH
#define D_  256

// output element offsets within d_out (element units of the storage dtype)
#define OFF_Y_  0L
#define OFF_FI_ 4194304L
#define OFF_IA_ 4210688L

typedef unsigned short u16;
typedef unsigned int   u32;
typedef short bf16x8 __attribute__((ext_vector_type(8)));
typedef float f32x4  __attribute__((ext_vector_type(4)));

__device__ __forceinline__ float bf2f(u16 u) {
  union { u32 u; float f; } x; x.u = ((u32)u) << 16; return x.f;
}
__device__ __forceinline__ u16 f2bf(float f) {
  union { float f; u32 u; } x; x.f = f;
  u32 r = (x.u + 0x7fffu + ((x.u >> 16) & 1u)) >> 16;
  return (u16)r;
}
__device__ __forceinline__ float gelu_exact(float v) {
  return 0.5f * v * (1.f + erff(v * 0.70710678118654752f));
}
__device__ __forceinline__ float sigmoidf_(float v) {
  return 1.f / (1.f + __expf(-v));
}
__device__ __forceinline__ float ldv(const void* p, long i, bool isf) {
  return isf ? ((const float*)p)[i] : bf2f(((const u16*)p)[i]);
}
__device__ __forceinline__ void stv(void* p, long i, float v, bool isf) {
  if (isf) ((float*)p)[i] = v;
  else ((u16*)p)[i] = f2bf(v);
}

// ---------------------------------------------------------------------------
// dtype detector (flag: 0 = bf16 storage, 1 = f32 storage)
// ---------------------------------------------------------------------------
__global__ void detect_dtype(const u16* __restrict__ x, u32* __restrict__ flag) {
  if (threadIdx.x == 0 && blockIdx.x == 0) {
    int good = 0;
    for (int i = 0; i < 512; ++i) {
      u16 v = x[i];
      int e = (v >> 7) & 0xFF;
      if (v == 0 || (e >= 100 && e <= 140)) ++good;
    }
    *flag = (good >= 450) ? 0u : 1u;
  }
}

// convert a small raw tensor (f32 or bf16) to bf16
__global__ __launch_bounds__(256)
void convert_in(const void* __restrict__ src, u16* __restrict__ dst, int n,
                const u32* __restrict__ flag) {
  const bool isf = (*flag != 0);
  int i = blockIdx.x * 256 + threadIdx.x;
  if (i < n) dst[i] = isf ? f2bf(((const float*)src)[i]) : ((const u16*)src)[i];
}

// fused transpose + convert: out[c][r] (bf16) = in[r][c] (raw). dims %32 == 0
__global__ void transpose_cvt(const void* __restrict__ in, u16* __restrict__ out,
                              int R, int C, const u32* __restrict__ flag) {
  const bool isf = (*flag != 0);
  __shared__ float t[32][33];
  const int c0 = blockIdx.x * 32, r0 = blockIdx.y * 32;
  const int tx = threadIdx.x, ty = threadIdx.y;
  for (int i = ty; i < 32; i += 8)
    t[i][tx] = ldv(in, (long)(r0 + i) * C + c0 + tx, isf);
  __syncthreads();
  for (int i = ty; i < 32; i += 8)
    out[(long)(c0 + i) * R + r0 + tx] = f2bf(t[tx][i]);
}

// ---------------------------------------------------------------------------
// K1: input-attention MLP (unchanged, passing)
// ---------------------------------------------------------------------------
__global__ __launch_bounds__(128)
void input_mlp2(const void* __restrict__ x,
                const void* __restrict__ w1, const void* __restrict__ b1,
                const void* __restrict__ w2, const void* __restrict__ b2,
                const u32* __restrict__ flag,
                u16* __restrict__ xg, void* __restrict__ dout) {
  const bool isf = (*flag != 0);
  const long row = blockIdx.x;
  const int tid = threadIdx.x;
  __shared__ float xr[F_];
  __shared__ float hid[32];
  __shared__ float red[2];
  float xv = ldv(x, row * F_ + tid, isf);
  xr[tid] = xv;
  __syncthreads();
  if (tid < 32) {
    float s = ldv(b1, tid, isf);
    for (int f = 0; f < F_; ++f) s += xr[f] * ldv(w1, f * 32 + tid, isf);
    hid[tid] = gelu_exact(s);
  }
  __syncthreads();
  float s = ldv(b2, tid, isf);
  #pragma unroll 8
  for (int j = 0; j < 32; ++j) s += hid[j] * ldv(w2, j * F_ + tid, isf);
  float ia = sigmoidf_(s);
  stv(dout, OFF_IA_ + row * F_ + tid, ia, isf);
  xg[row * F_ + tid] = f2bf(ia * xv);
  float v = ia;
  for (int o = 32; o > 0; o >>= 1) v += __shfl_down(v, o);
  if ((tid & 63) == 0) red[tid >> 6] = v;
  __syncthreads();
  if (tid == 0) stv(dout, OFF_FI_ + row, red[0] + red[1], isf);
}

// ---------------------------------------------------------------------------
// K2 v3: gate-parallel GRU bank. One 32-lane half-wave per (b,f) recurrence;
// lane g in [0,24) owns gate g (r: 0-7, z: 8-15, n: 16-23). h broadcast via shfl.
// grid = 1024 blocks x 256 threads (8 recurrences/block) = 4096 waves (16/CU).
// ---------------------------------------------------------------------------
__global__ __launch_bounds__(256)
void gru_scan3(const u16* __restrict__ xg, const void* __restrict__ W_ih,
               const void* __restrict__ W_hh, const void* __restrict__ b_ih,
               const void* __restrict__ b_hh, const u32* __restrict__ flag,
               u16* __restrict__ gruo) {
  const bool isf = (*flag != 0);
  const int tid = threadIdx.x;
  const int sub = tid >> 5;              // recurrence slot in block (0..7)
  const int g   = tid & 31;              // gate lane; 24..31 idle
  const int rec = blockIdx.x * 8 + sub;  // rec = b*128 + f  (f fastest)
  const int b = rec >> 7, f = rec & 127;
  const int base = tid & 32;             // shfl base of this half-wave (0 or 32)
  const bool active = (g < 24);
  const bool is_n = (g >= 16) && active;
  float whh[8], wihg = 0.f, cb = 0.f, bin_g = 0.f, bhn_g = 0.f;
  if (active) {
    #pragma unroll
    for (int j = 0; j < 8; ++j) whh[j] = ldv(W_hh, (long)f * 192 + g * 8 + j, isf);
    wihg = ldv(W_ih, f * 24 + g, isf);
    if (g < 16) {
      cb = ldv(b_ih, f * 24 + g, isf) + ldv(b_hh, f * 24 + g, isf);
    } else {
      bin_g = ldv(b_ih, f * 24 + g, isf);
      bhn_g = ldv(b_hh, f * 24 + g, isf);
    }
  } else {
    #pragma unroll
    for (int j = 0; j < 8; ++j) whh[j] = 0.f;
  }
  float h[8];
  #pragma unroll
  for (int j = 0; j < 8; ++j) h[j] = 0.f;
  const u16* xp = xg + (long)b * T_ * F_ + f;
  u16* op = gruo + (long)b * T_ * E_ + f * 8;   // + (g-16) at store
  float xv = bf2f(xp[0]);
  const int ri = base + (g & 15);       // n-lane g=16+j -> reads lane base+j   (r)
  const int zi = base + 8 + (g & 7);    // n-lane g=16+j -> reads lane base+8+j (z)
  for (int t = 0; t < T_; ++t) {
    float xn = (t + 1 < T_) ? bf2f(xp[(t + 1) * F_]) : 0.f;  // prefetch
    float gh = h[0] * whh[0];
    #pragma unroll
    for (int j = 1; j < 8; ++j) gh = fmaf(h[j], whh[j], gh);
    // r/z lanes: s = sigmoid(x*wih + gh + (b_ih+b_hh)); n lanes: p,q parts
    float s = sigmoidf_(fmaf(xv, wihg, gh + cb));
    float p = fmaf(xv, wihg, bin_g);
    float q = gh + bhn_g;
    float r = __shfl(s, ri);
    float z = __shfl(s, zi);
    float hn = 0.f;
    if (is_n) {
      float a = fmaf(r, q, p);
      float e = __expf(2.f * a);
      float n = 1.f - 2.f / (e + 1.f);  // tanh(a)
      hn = (1.f - z) * n + z * h[g - 16];
      op[(long)t * E_ + (g - 16)] = f2bf(hn);
    }
    #pragma unroll
    for (int j = 0; j < 8; ++j) h[j] = __shfl(hn, base + 16 + j);
    xv = xn;
  }
}

// ---------------------------------------------------------------------------
// bt-form MFMA GEMM (unchanged, passing): C[m][n] = sum_k A[m][k]*B[n][k]
// EPI: 0=none, 1=+bias, 2=+bias+gelu, 3=+bias+resid, 4=+bias & V-transpose write
// COUT: 1 -> final y output, dtype-flagged store
// ---------------------------------------------------------------------------
template <int EPI, int COUT>
__global__ __launch_bounds__(256)
void gemm_bt(const u16* __restrict__ A, int lda, long abs_,
             const u16* __restrict__ Bp, int ldb, long bbs_,
             void* __restrict__ Cg, int ldc, long cbs_o, long cbs_i, int cmod,
             const u16* __restrict__ bias, const u16* __restrict__ resid,
             int K, int nbm, const u32* __restrict__ flag) {
  const bool isf = (*flag != 0);
  const int z = blockIdx.y;
  const int bm = blockIdx.x % nbm, bn = blockIdx.x / nbm;
  const int w = threadIdx.x >> 6, lane = threadIdx.x & 63;
  A += (long)z * abs_;
  Bp += (long)z * bbs_;
  const long coff = (long)(z / cmod) * cbs_o + (long)(z % cmod) * cbs_i;
  __shared__ __align__(16) u16 As[128 * 32];
  __shared__ __align__(16) u16 Bs[128 * 32];
  const long m0 = (long)bm * 128, n0 = (long)bn * 128;
  const int wm = w >> 1, wn = w & 1;
  const int rr = lane >> 2, cc = lane & 3;
  const int r0 = w * 32 + rr, r1 = r0 + 16;
  const u16* pa0 = A + (m0 + r0) * (long)lda + cc * 8;
  const u16* pa1 = A + (m0 + r1) * (long)lda + cc * 8;
  const u16* pb0 = Bp + (n0 + r0) * (long)ldb + cc * 8;
  const u16* pb1 = Bp + (n0 + r1) * (long)ldb + cc * 8;
  u16* sa0 = &As[r0 * 32 + cc * 8]; u16* sa1 = &As[r1 * 32 + cc * 8];
  u16* sb0 = &Bs[r0 * 32 + cc * 8]; u16* sb1 = &Bs[r1 * 32 + cc * 8];
  f32x4 acc[4][4] = {};
  const int nk = K >> 5;
  const int lr = lane & 15, lk = (lane >> 4) * 8;
  for (int kt = 0; kt < nk; ++kt) {
    const int k0 = kt << 5;
    uint4 va0 = *(const uint4*)(pa0 + k0);
    uint4 va1 = *(const uint4*)(pa1 + k0);
    uint4 vb0 = *(const uint4*)(pb0 + k0);
    uint4 vb1 = *(const uint4*)(pb1 + k0);
    __syncthreads();
    *(uint4*)sa0 = va0; *(uint4*)sa1 = va1;
    *(uint4*)sb0 = vb0; *(uint4*)sb1 = vb1;
    __syncthreads();
    bf16x8 af[4], bfv[4];
    #pragma unroll
    for (int i = 0; i < 4; ++i)
      af[i] = *(const bf16x8*)&As[(wm * 64 + i * 16 + lr) * 32 + lk];
    #pragma unroll
    for (int i = 0; i < 4; ++i)
      bfv[i] = *(const bf16x8*)&Bs[(wn * 64 + i * 16 + lr) * 32 + lk];
    #pragma unroll
    for (int i = 0; i < 4; ++i) {
      #pragma unroll
      for (int j = 0; j < 4; ++j)
        acc[i][j] = __builtin_amdgcn_mfma_f32_16x16x32_bf16(af[i], bfv[j], acc[i][j], 0, 0, 0);
    }
  }
  const int rq = (lane >> 4) * 4;
  #pragma unroll
  for (int j = 0; j < 4; ++j) {
    const long col = n0 + wn * 64 + j * 16 + lr;
    const float bv = (EPI >= 1) ? bf2f(bias[col]) : 0.f;
    #pragma unroll
    for (int i = 0; i < 4; ++i) {
      const long row0 = m0 + wm * 64 + i * 16 + rq;
      #pragma unroll
      for (int q = 0; q < 4; ++q) {
        const long row = row0 + q;
        float v = acc[i][j][q] + bv;
        if (EPI == 2) v = gelu_exact(v);
        if (EPI == 3) v += bf2f(resid[row * (long)ldc + col]);
        if (EPI == 4) {
          const long idx = (((row >> 8) * 4 + (col >> 8)) * 256 + (col & 255)) * 256 + (row & 255);
          ((u16*)Cg)[idx] = f2bf(v);
        } else if (COUT) {
          stv(Cg, coff + row * (long)ldc + col, v, isf);
        } else {
          ((u16*)Cg)[coff + row * (long)ldc + col] = f2bf(v);
        }
      }
    }
  }
}

// ---------------------------------------------------------------------------
// ATT1 (unchanged, passing): P[z][t][s] = softmax_s(q.k/16), QK layout [B,T,2E]
// ---------------------------------------------------------------------------
__global__ __launch_bounds__(256)
void attn_qk_softmax(const u16* __restrict__ qk, u16* __restrict__ P) {
  const int z = blockIdx.y, bb = z >> 2, hh = z & 3;
  const int w = threadIdx.x >> 6, lane = threadIdx.x & 63;
  const long t0 = (long)blockIdx.x * 64;
  __shared__ __align__(16) u16 Qs[64 * 32];
  __shared__ __align__(16) u16 Ks[256 * 32];
  const u16* qb = qk + (long)bb * T_ * 2 * E_ + hh * HD_;
  const u16* kb = qb + E_;
  const int rr = lane >> 2, cc = lane & 3;
  const int lr = lane & 15, lk = (lane >> 4) * 8;
  f32x4 acc[16] = {};
  for (int kt = 0; kt < 8; ++kt) {
    const int k0 = kt * 32;
    uint4 vq = *(const uint4*)(qb + (t0 + w * 16 + rr) * (2L * E_) + k0 + cc * 8);
    uint4 vk[4];
    #pragma unroll
    for (int c = 0; c < 4; ++c)
      vk[c] = *(const uint4*)(kb + (long)(w * 64 + c * 16 + rr) * (2L * E_) + k0 + cc * 8);
    __syncthreads();
    *(uint4*)&Qs[(w * 16 + rr) * 32 + cc * 8] = vq;
    #pragma unroll
    for (int c = 0; c < 4; ++c)
      *(uint4*)&Ks[(w * 64 + c * 16 + rr) * 32 + cc * 8] = vk[c];
    __syncthreads();
    bf16x8 aq = *(const bf16x8*)&Qs[(w * 16 + lr) * 32 + lk];
    #pragma unroll
    for (int nt = 0; nt < 16; ++nt) {
      bf16x8 bk = *(const bf16x8*)&Ks[(nt * 16 + lr) * 32 + lk];
      acc[nt] = __builtin_amdgcn_mfma_f32_16x16x32_bf16(aq, bk, acc[nt], 0, 0, 0);
    }
  }
  u16* Pp = P + (long)z * (T_ * T_);
  #pragma unroll
  for (int q = 0; q < 4; ++q) {
    float mx = -3.4e38f;
    #pragma unroll
    for (int nt = 0; nt < 16; ++nt) mx = fmaxf(mx, acc[nt][q]);
    mx = fmaxf(mx, __shfl_xor(mx, 1));
    mx = fmaxf(mx, __shfl_xor(mx, 2));
    mx = fmaxf(mx, __shfl_xor(mx, 4));
    mx = fmaxf(mx, __shfl_xor(mx, 8));
    float e[16], sum = 0.f;
    #pragma unroll
    for (int nt = 0; nt < 16; ++nt) {
      e[nt] = __expf((acc[nt][q] - mx) * 0.0625f);
      sum += e[nt];
    }
    sum += __shfl_xor(sum, 1);
    sum += __shfl_xor(sum, 2);
    sum += __shfl_xor(sum, 4);
    sum += __shfl_xor(sum, 8);
    const float inv = 1.f / sum;
    const long rowg = t0 + w * 16 + (lane >> 4) * 4 + q;
    #pragma unroll
    for (int nt = 0; nt < 16; ++nt)
      Pp[rowg * T_ + nt * 16 + (lane & 15)] = f2bf(e[nt] * inv);
  }
}

// ---------------------------------------------------------------------------
extern "C" void kernel_launch(void* const* d_in, const int* in_sizes, int n_in,
                              void* d_out, int out_size, void* d_ws, size_t ws_size,
                              hipStream_t stream) {
  (void)in_sizes; (void)n_in; (void)out_size; (void)ws_size;
  char* ws = (char*)d_ws;
  // ws layout (bytes), peak ~151MB (proven safe: round 2 wrote 165.7MB cleanly)
  u16* BIASA = (u16*)(ws + 0);          // bf16 biases: ipb@0(3072) mhb@3072 opb@4096 fb1@4352 fb2@4864
  u32* FLAG  = (u32*)(ws + 12288);
  u16* wtI   = (u16*)(ws + 65536);      // [3072][1024] 6.29MB
  u16* wtM   = (u16*)(ws + 6356992);    // [1024][1024] 2.10MB
  u16* wtO   = (u16*)(ws + 8454144);    // [256][1024]  0.52MB
  u16* wtF1  = (u16*)(ws + 8978432);    // [512][256]
  u16* wtF2  = (u16*)(ws + 9240576);    // [256][512]   -> ends 9502720
  u16* XG    = (u16*)(ws + 9502720);    // [B,T,F] 4.19MB (dead after gru)
  u16* GRUO  = (u16*)(ws + 16777216);   // [B,T,E] 33.55MB (dead after V gemm)
  u16* Pbuf  = GRUO;                    // [B*NH][T][T] overlay (dead after PV)
  u16* H1    = (u16*)(ws + 16777216);   // [B,T,D] overlay on dead P
  u16* FFH   = (u16*)(ws + 25165824);   // [B,T,2D] overlay on dead P
  u16* QK    = (u16*)(ws + 50331648);   // [B,T,2E] 67.1MB (dead after attn)
  u16* CTX   = QK;                      // [B,T,E] overlay on dead QK
  u16* MHA   = (u16*)(ws + 83886080);   // [B,T,E] overlay on dead QK tail
  u16* VT    = (u16*)(ws + 117440512);  // [B*NH][HD][T] 33.55MB -> ends 150994944

  detect_dtype<<<1, 64, 0, stream>>>((const u16*)d_in[0], FLAG);

  // biases -> bf16 arena
  convert_in<<<12, 256, 0, stream>>>(d_in[10], BIASA + 0,    3072, FLAG);
  convert_in<<<4,  256, 0, stream>>>(d_in[12], BIASA + 3072, 1024, FLAG);
  convert_in<<<1,  256, 0, stream>>>(d_in[14], BIASA + 4096, 256,  FLAG);
  convert_in<<<2,  256, 0, stream>>>(d_in[16], BIASA + 4352, 512,  FLAG);
  convert_in<<<1,  256, 0, stream>>>(d_in[18], BIASA + 4864, 256,  FLAG);

  dim3 tb(32, 8);
  transpose_cvt<<<dim3(3072 / 32, 1024 / 32), tb, 0, stream>>>(d_in[9],  wtI,  1024, 3072, FLAG);
  transpose_cvt<<<dim3(1024 / 32, 1024 / 32), tb, 0, stream>>>(d_in[11], wtM,  1024, 1024, FLAG);
  transpose_cvt<<<dim3(256 / 32, 1024 / 32),  tb, 0, stream>>>(d_in[13], wtO,  1024, 256,  FLAG);
  transpose_cvt<<<dim3(512 / 32, 256 / 32),   tb, 0, stream>>>(d_in[15], wtF1, 256,  512,  FLAG);
  transpose_cvt<<<dim3(256 / 32, 512 / 32),   tb, 0, stream>>>(d_in[17], wtF2, 512,  256,  FLAG);

  input_mlp2<<<B_ * T_, 128, 0, stream>>>(d_in[0], d_in[1], d_in[2], d_in[3], d_in[4],
                                          FLAG, XG, d_out);
  gru_scan3<<<1024, 256, 0, stream>>>(XG, d_in[5], d_in[6], d_in[7], d_in[8], FLAG, GRUO);

  // qk = gruo @ Wqk + b   (M=16384, N=2048, K=1024)
  gemm_bt<1, 0><<<dim3(128 * 16, 1), 256, 0, stream>>>(GRUO, 1024, 0, wtI, 1024, 0,
      QK, 2048, 0, 0, 1, BIASA, nullptr, 1024, 128, FLAG);
  // vt = (gruo @ Wv + b)^T per head  -> VT[z][d][s]
  gemm_bt<4, 0><<<dim3(128 * 8, 1), 256, 0, stream>>>(GRUO, 1024, 0, wtI + 2048 * 1024, 1024, 0,
      VT, 0, 0, 0, 1, BIASA + 2048, nullptr, 1024, 128, FLAG);
  // P = softmax(QK^T/16)
  attn_qk_softmax<<<dim3(T_ / 64, B_ * NH_), 256, 0, stream>>>(QK, Pbuf);
  // ctx = P @ V  (batched z=256)
  gemm_bt<0, 0><<<dim3(2 * 2, B_ * NH_), 256, 0, stream>>>(Pbuf, 256, 65536, VT, 256, 65536,
      CTX, 1024, (long)T_ * E_, 256, 4, nullptr, nullptr, 256, 2, FLAG);
  // mha = ctx @ mha_out_w + b
  gemm_bt<1, 0><<<dim3(128 * 8, 1), 256, 0, stream>>>(CTX, 1024, 0, wtM, 1024, 0,
      MHA, 1024, 0, 0, 1, BIASA + 3072, nullptr, 1024, 128, FLAG);
  // h1 = mha @ outp_w + b
  gemm_bt<1, 0><<<dim3(128 * 2, 1), 256, 0, stream>>>(MHA, 1024, 0, wtO, 1024, 0,
      H1, 256, 0, 0, 1, BIASA + 4096, nullptr, 1024, 128, FLAG);
  // ffh = gelu(h1 @ ffn_w1 + b)
  gemm_bt<2, 0><<<dim3(128 * 4, 1), 256, 0, stream>>>(H1, 256, 0, wtF1, 256, 0,
      FFH, 512, 0, 0, 1, BIASA + 4352, nullptr, 256, 128, FLAG);
  // y = h1 + ffh @ ffn_w2 + b  -> final output (flagged dtype)
  gemm_bt<3, 1><<<dim3(128 * 2, 1), 256, 0, stream>>>(FFH, 512, 0, wtF2, 512, 0,
      d_out, 256, 0, 0, 1, BIASA + 4864, H1, 512, 128, FLAG);
}

// Round 7
// 544.083 us; speedup vs baseline: 13.9979x; 1.2142x over previous
//
#include <hip/hip_runtime.h>
#include <hip/hip_bf16.h>
#include <math.h>

// Problem dims
#define B_  64
#define T_  256
#define F_  128
#define H_  8
#define E_  1024   // F*H
#define NH_ 4
#define HD_ 256    // E/NH
#define D_  256

// output element offsets within d_out (element units of the storage dtype)
#define OFF_Y_  0L
#define OFF_FI_ 4194304L
#define OFF_IA_ 4210688L

typedef unsigned short u16;
typedef unsigned int   u32;
typedef short bf16x8 __attribute__((ext_vector_type(8)));
typedef float f32x4  __attribute__((ext_vector_type(4)));

__device__ __forceinline__ float bf2f(u16 u) {
  union { u32 u; float f; } x; x.u = ((u32)u) << 16; return x.f;
}
__device__ __forceinline__ u16 f2bf(float f) {
  union { float f; u32 u; } x; x.f = f;
  u32 r = (x.u + 0x7fffu + ((x.u >> 16) & 1u)) >> 16;
  return (u16)r;
}
__device__ __forceinline__ float gelu_exact(float v) {
  return 0.5f * v * (1.f + erff(v * 0.70710678118654752f));
}
__device__ __forceinline__ float sigmoidf_(float v) {
  return 1.f / (1.f + __expf(-v));
}
__device__ __forceinline__ float ldv(const void* p, long i, bool isf) {
  return isf ? ((const float*)p)[i] : bf2f(((const u16*)p)[i]);
}
__device__ __forceinline__ void stv(void* p, long i, float v, bool isf) {
  if (isf) ((float*)p)[i] = v;
  else ((u16*)p)[i] = f2bf(v);
}
// async global->LDS, 16B/lane: LDS dest = wave-uniform base + lane*16 (HW)
__device__ __forceinline__ void gld16(void* lds, const void* g) {
  __builtin_amdgcn_global_load_lds(
      (const __attribute__((address_space(1))) u32*)g,
      (__attribute__((address_space(3))) u32*)lds, 16, 0, 0);
}

// ---------------------------------------------------------------------------
// dtype detector (flag: 0 = bf16 storage, 1 = f32 storage)
// ---------------------------------------------------------------------------
__global__ void detect_dtype(const u16* __restrict__ x, u32* __restrict__ flag) {
  if (threadIdx.x == 0 && blockIdx.x == 0) {
    int good = 0;
    for (int i = 0; i < 512; ++i) {
      u16 v = x[i];
      int e = (v >> 7) & 0xFF;
      if (v == 0 || (e >= 100 && e <= 140)) ++good;
    }
    *flag = (good >= 450) ? 0u : 1u;
  }
}

// convert a small raw tensor (f32 or bf16) to bf16
__global__ __launch_bounds__(256)
void convert_in(const void* __restrict__ src, u16* __restrict__ dst, int n,
                const u32* __restrict__ flag) {
  const bool isf = (*flag != 0);
  int i = blockIdx.x * 256 + threadIdx.x;
  if (i < n) dst[i] = isf ? f2bf(((const float*)src)[i]) : ((const u16*)src)[i];
}

// fused transpose + convert: out[c][r] (bf16) = in[r][c] (raw). dims %32 == 0
__global__ void transpose_cvt(const void* __restrict__ in, u16* __restrict__ out,
                              int R, int C, const u32* __restrict__ flag) {
  const bool isf = (*flag != 0);
  __shared__ float t[32][33];
  const int c0 = blockIdx.x * 32, r0 = blockIdx.y * 32;
  const int tx = threadIdx.x, ty = threadIdx.y;
  for (int i = ty; i < 32; i += 8)
    t[i][tx] = ldv(in, (long)(r0 + i) * C + c0 + tx, isf);
  __syncthreads();
  for (int i = ty; i < 32; i += 8)
    out[(long)(c0 + i) * R + r0 + tx] = f2bf(t[tx][i]);
}

// ---------------------------------------------------------------------------
// K1: input-attention MLP (unchanged, passing)
// ---------------------------------------------------------------------------
__global__ __launch_bounds__(128)
void input_mlp2(const void* __restrict__ x,
                const void* __restrict__ w1, const void* __restrict__ b1,
                const void* __restrict__ w2, const void* __restrict__ b2,
                const u32* __restrict__ flag,
                u16* __restrict__ xg, void* __restrict__ dout) {
  const bool isf = (*flag != 0);
  const long row = blockIdx.x;
  const int tid = threadIdx.x;
  __shared__ float xr[F_];
  __shared__ float hid[32];
  __shared__ float red[2];
  float xv = ldv(x, row * F_ + tid, isf);
  xr[tid] = xv;
  __syncthreads();
  if (tid < 32) {
    float s = ldv(b1, tid, isf);
    for (int f = 0; f < F_; ++f) s += xr[f] * ldv(w1, f * 32 + tid, isf);
    hid[tid] = gelu_exact(s);
  }
  __syncthreads();
  float s = ldv(b2, tid, isf);
  #pragma unroll 8
  for (int j = 0; j < 32; ++j) s += hid[j] * ldv(w2, j * F_ + tid, isf);
  float ia = sigmoidf_(s);
  stv(dout, OFF_IA_ + row * F_ + tid, ia, isf);
  xg[row * F_ + tid] = f2bf(ia * xv);
  float v = ia;
  for (int o = 32; o > 0; o >>= 1) v += __shfl_down(v, o);
  if ((tid & 63) == 0) red[tid >> 6] = v;
  __syncthreads();
  if (tid == 0) stv(dout, OFF_FI_ + row, red[0] + red[1], isf);
}

// ---------------------------------------------------------------------------
// K2 v4: GRU bank, 8 lanes per recurrence. Lane j owns gates (r_j, z_j, n_j):
// 24 local FMAs/step, no idle lanes, no divergence. h exchanged via LDS
// (wave-synchronous: each 8-lane group reads only its own row).
// grid = 256 blocks x 256 threads -> 1024 waves (1 per SIMD), 32 recs/block.
// ---------------------------------------------------------------------------
__global__ __launch_bounds__(256)
void gru_scan4(const u16* __restrict__ xg, const void* __restrict__ W_ih,
               const void* __restrict__ W_hh, const void* __restrict__ b_ih,
               const void* __restrict__ b_hh, const u32* __restrict__ flag,
               u16* __restrict__ gruo) {
  const bool isf = (*flag != 0);
  const int tid = threadIdx.x;
  const int ric = tid >> 3;              // recurrence slot in block (0..31)
  const int j   = tid & 7;               // owned hidden/gate index
  const int rec = blockIdx.x * 32 + ric; // rec = b*128 + f
  const int b = rec >> 7, f = rec & 127;
  __shared__ __align__(16) float hbuf[32][8];
  float whr[8], whz[8], whn[8];
  #pragma unroll
  for (int k = 0; k < 8; ++k) {
    whr[k] = ldv(W_hh, (long)f * 192 + j * 8 + k, isf);
    whz[k] = ldv(W_hh, (long)f * 192 + (8 + j) * 8 + k, isf);
    whn[k] = ldv(W_hh, (long)f * 192 + (16 + j) * 8 + k, isf);
  }
  const float wir = ldv(W_ih, f * 24 + j, isf);
  const float wiz = ldv(W_ih, f * 24 + 8 + j, isf);
  const float win = ldv(W_ih, f * 24 + 16 + j, isf);
  const float cbr = ldv(b_ih, f * 24 + j, isf) + ldv(b_hh, f * 24 + j, isf);
  const float cbz = ldv(b_ih, f * 24 + 8 + j, isf) + ldv(b_hh, f * 24 + 8 + j, isf);
  const float bin_ = ldv(b_ih, f * 24 + 16 + j, isf);
  const float bhn_ = ldv(b_hh, f * 24 + 16 + j, isf);
  float h[8];
  #pragma unroll
  for (int k = 0; k < 8; ++k) h[k] = 0.f;
  const u16* xp = xg + (long)b * T_ * F_ + f;
  u16* op = gruo + (long)b * T_ * E_ + f * 8 + j;
  float xv = bf2f(xp[0]);
  for (int t = 0; t < T_; ++t) {
    float xn = (t + 1 < T_) ? bf2f(xp[(t + 1) * F_]) : 0.f;  // prefetch
    float ar = fmaf(xv, wir, cbr);
    float az = fmaf(xv, wiz, cbz);
    float an = bhn_;
    #pragma unroll
    for (int k = 0; k < 8; ++k) {
      ar = fmaf(h[k], whr[k], ar);
      az = fmaf(h[k], whz[k], az);
      an = fmaf(h[k], whn[k], an);
    }
    const float r = sigmoidf_(ar);
    const float z = sigmoidf_(az);
    const float a = fmaf(r, an, fmaf(xv, win, bin_));
    const float e = __expf(2.f * a);
    const float n = 1.f - 2.f / (e + 1.f);   // tanh(a)
    const float hn = fmaf(z, h[j] - n, n);   // (1-z)*n + z*h[j]
    op[(long)t * E_] = f2bf(hn);
    hbuf[ric][j] = hn;
    // wave-synchronous exchange: group reads only lanes of the same wave
    f32x4 h0 = *(const f32x4*)&hbuf[ric][0];
    f32x4 h1 = *(const f32x4*)&hbuf[ric][4];
    h[0] = h0[0]; h[1] = h0[1]; h[2] = h0[2]; h[3] = h0[3];
    h[4] = h1[0]; h[5] = h1[1]; h[6] = h1[2]; h[7] = h1[3];
    xv = xn;
  }
}

// ---------------------------------------------------------------------------
// bt-form MFMA GEMM: C[m][n] = sum_k A[m][k]*B[n][k]  (+epilogues)
// 128x128 tile, BK=32, 4 waves, global_load_lds width-16 staging (m97 form).
// EPI: 0=none, 1=+bias, 2=+bias+gelu, 3=+bias+resid, 4=+bias & V-transpose write
// COUT: 1 -> final y output, dtype-flagged store
// ---------------------------------------------------------------------------
template <int EPI, int COUT>
__global__ __launch_bounds__(256)
void gemm_bt(const u16* __restrict__ A, int lda, long abs_,
             const u16* __restrict__ Bp, int ldb, long bbs_,
             void* __restrict__ Cg, int ldc, long cbs_o, long cbs_i, int cmod,
             const u16* __restrict__ bias, const u16* __restrict__ resid,
             int K, int nbm, const u32* __restrict__ flag) {
  const bool isf = (*flag != 0);
  const int z = blockIdx.y;
  const int bm = blockIdx.x % nbm, bn = blockIdx.x / nbm;
  const int w = threadIdx.x >> 6, lane = threadIdx.x & 63;
  A += (long)z * abs_;
  Bp += (long)z * bbs_;
  const long coff = (long)(z / cmod) * cbs_o + (long)(z % cmod) * cbs_i;
  __shared__ __align__(16) u16 As[128 * 32];
  __shared__ __align__(16) u16 Bs[128 * 32];
  const long m0 = (long)bm * 128, n0 = (long)bn * 128;
  const int wm = w >> 1, wn = w & 1;
  const int rr = lane >> 2, cc = lane & 3;   // lane i -> row rr, 8-col chunk cc
  f32x4 acc[4][4] = {};
  const int nk = K >> 5;
  const int lr = lane & 15, lk = (lane >> 4) * 8;
  for (int kt = 0; kt < nk; ++kt) {
    const int k0 = kt << 5;
    __syncthreads();
    #pragma unroll
    for (int c = 0; c < 2; ++c) {
      const int rb = w * 32 + c * 16;   // wave-uniform LDS base (16 rows x 64B)
      gld16((char*)As + rb * 64, A + (m0 + rb + rr) * (long)lda + k0 + cc * 8);
      gld16((char*)Bs + rb * 64, Bp + (n0 + rb + rr) * (long)ldb + k0 + cc * 8);
    }
    __syncthreads();
    bf16x8 af[4], bfv[4];
    #pragma unroll
    for (int i = 0; i < 4; ++i)
      af[i] = *(const bf16x8*)&As[(wm * 64 + i * 16 + lr) * 32 + lk];
    #pragma unroll
    for (int i = 0; i < 4; ++i)
      bfv[i] = *(const bf16x8*)&Bs[(wn * 64 + i * 16 + lr) * 32 + lk];
    #pragma unroll
    for (int i = 0; i < 4; ++i) {
      #pragma unroll
      for (int j = 0; j < 4; ++j)
        acc[i][j] = __builtin_amdgcn_mfma_f32_16x16x32_bf16(af[i], bfv[j], acc[i][j], 0, 0, 0);
    }
  }
  const int rq = (lane >> 4) * 4;
  #pragma unroll
  for (int j = 0; j < 4; ++j) {
    const long col = n0 + wn * 64 + j * 16 + lr;
    const float bv = (EPI >= 1) ? bf2f(bias[col]) : 0.f;
    #pragma unroll
    for (int i = 0; i < 4; ++i) {
      const long row0 = m0 + wm * 64 + i * 16 + rq;
      #pragma unroll
      for (int q = 0; q < 4; ++q) {
        const long row = row0 + q;
        float v = acc[i][j][q] + bv;
        if (EPI == 2) v = gelu_exact(v);
        if (EPI == 3) v += bf2f(resid[row * (long)ldc + col]);
        if (EPI == 4) {
          const long idx = (((row >> 8) * 4 + (col >> 8)) * 256 + (col & 255)) * 256 + (row & 255);
          ((u16*)Cg)[idx] = f2bf(v);
        } else if (COUT) {
          stv(Cg, coff + row * (long)ldc + col, v, isf);
        } else {
          ((u16*)Cg)[coff + row * (long)ldc + col] = f2bf(v);
        }
      }
    }
  }
}

// ---------------------------------------------------------------------------
// ATT1: P[z][t][s] = softmax_s(q.k/16), QK layout [B,T,2E], gld16 staging
// ---------------------------------------------------------------------------
__global__ __launch_bounds__(256)
void attn_qk_softmax(const u16* __restrict__ qk, u16* __restrict__ P) {
  const int z = blockIdx.y, bb = z >> 2, hh = z & 3;
  const int w = threadIdx.x >> 6, lane = threadIdx.x & 63;
  const long t0 = (long)blockIdx.x * 64;
  __shared__ __align__(16) u16 Qs[64 * 32];
  __shared__ __align__(16) u16 Ks[256 * 32];
  const u16* qb = qk + (long)bb * T_ * 2 * E_ + hh * HD_;
  const u16* kb = qb + E_;
  const int rr = lane >> 2, cc = lane & 3;
  const int lr = lane & 15, lk = (lane >> 4) * 8;
  f32x4 acc[16] = {};
  for (int kt = 0; kt < 8; ++kt) {
    const int k0 = kt * 32;
    __syncthreads();
    gld16((char*)Qs + w * 16 * 64, qb + (t0 + w * 16 + rr) * (2L * E_) + k0 + cc * 8);
    #pragma unroll
    for (int c = 0; c < 4; ++c) {
      const int rb = w * 64 + c * 16;
      gld16((char*)Ks + rb * 64, kb + (long)(rb + rr) * (2L * E_) + k0 + cc * 8);
    }
    __syncthreads();
    bf16x8 aq = *(const bf16x8*)&Qs[(w * 16 + lr) * 32 + lk];
    #pragma unroll
    for (int nt = 0; nt < 16; ++nt) {
      bf16x8 bk = *(const bf16x8*)&Ks[(nt * 16 + lr) * 32 + lk];
      acc[nt] = __builtin_amdgcn_mfma_f32_16x16x32_bf16(aq, bk, acc[nt], 0, 0, 0);
    }
  }
  u16* Pp = P + (long)z * (T_ * T_);
  #pragma unroll
  for (int q = 0; q < 4; ++q) {
    float mx = -3.4e38f;
    #pragma unroll
    for (int nt = 0; nt < 16; ++nt) mx = fmaxf(mx, acc[nt][q]);
    mx = fmaxf(mx, __shfl_xor(mx, 1));
    mx = fmaxf(mx, __shfl_xor(mx, 2));
    mx = fmaxf(mx, __shfl_xor(mx, 4));
    mx = fmaxf(mx, __shfl_xor(mx, 8));
    float e[16], sum = 0.f;
    #pragma unroll
    for (int nt = 0; nt < 16; ++nt) {
      e[nt] = __expf((acc[nt][q] - mx) * 0.0625f);
      sum += e[nt];
    }
    sum += __shfl_xor(sum, 1);
    sum += __shfl_xor(sum, 2);
    sum += __shfl_xor(sum, 4);
    sum += __shfl_xor(sum, 8);
    const float inv = 1.f / sum;
    const long rowg = t0 + w * 16 + (lane >> 4) * 4 + q;
    #pragma unroll
    for (int nt = 0; nt < 16; ++nt)
      Pp[rowg * T_ + nt * 16 + (lane & 15)] = f2bf(e[nt] * inv);
  }
}

// ---------------------------------------------------------------------------
extern "C" void kernel_launch(void* const* d_in, const int* in_sizes, int n_in,
                              void* d_out, int out_size, void* d_ws, size_t ws_size,
                              hipStream_t stream) {
  (void)in_sizes; (void)n_in; (void)out_size; (void)ws_size;
  char* ws = (char*)d_ws;
  // ws layout (bytes), peak ~151MB (proven safe: round 2 wrote 165.7MB cleanly)
  u16* BIASA = (u16*)(ws + 0);          // bf16 biases: ipb@0(3072) mhb@3072 opb@4096 fb1@4352 fb2@4864
  u32* FLAG  = (u32*)(ws + 12288);
  u16* wtI   = (u16*)(ws + 65536);      // [3072][1024] 6.29MB
  u16* wtM   = (u16*)(ws + 6356992);    // [1024][1024] 2.10MB
  u16* wtO   = (u16*)(ws + 8454144);    // [256][1024]  0.52MB
  u16* wtF1  = (u16*)(ws + 8978432);    // [512][256]
  u16* wtF2  = (u16*)(ws + 9240576);    // [256][512]   -> ends 9502720
  u16* XG    = (u16*)(ws + 9502720);    // [B,T,F] 4.19MB (dead after gru)
  u16* GRUO  = (u16*)(ws + 16777216);   // [B,T,E] 33.55MB (dead after V gemm)
  u16* Pbuf  = GRUO;                    // [B*NH][T][T] overlay (dead after PV)
  u16* H1    = (u16*)(ws + 16777216);   // [B,T,D] overlay on dead P
  u16* FFH   = (u16*)(ws + 25165824);   // [B,T,2D] overlay on dead P
  u16* QK    = (u16*)(ws + 50331648);   // [B,T,2E] 67.1MB (dead after attn)
  u16* CTX   = QK;                      // [B,T,E] overlay on dead QK
  u16* MHA   = (u16*)(ws + 83886080);   // [B,T,E] overlay on dead QK tail
  u16* VT    = (u16*)(ws + 117440512);  // [B*NH][HD][T] 33.55MB -> ends 150994944

  detect_dtype<<<1, 64, 0, stream>>>((const u16*)d_in[0], FLAG);

  // biases -> bf16 arena
  convert_in<<<12, 256, 0, stream>>>(d_in[10], BIASA + 0,    3072, FLAG);
  convert_in<<<4,  256, 0, stream>>>(d_in[12], BIASA + 3072, 1024, FLAG);
  convert_in<<<1,  256, 0, stream>>>(d_in[14], BIASA + 4096, 256,  FLAG);
  convert_in<<<2,  256, 0, stream>>>(d_in[16], BIASA + 4352, 512,  FLAG);
  convert_in<<<1,  256, 0, stream>>>(d_in[18], BIASA + 4864, 256,  FLAG);

  dim3 tb(32, 8);
  transpose_cvt<<<dim3(3072 / 32, 1024 / 32), tb, 0, stream>>>(d_in[9],  wtI,  1024, 3072, FLAG);
  transpose_cvt<<<dim3(1024 / 32, 1024 / 32), tb, 0, stream>>>(d_in[11], wtM,  1024, 1024, FLAG);
  transpose_cvt<<<dim3(256 / 32, 1024 / 32),  tb, 0, stream>>>(d_in[13], wtO,  1024, 256,  FLAG);
  transpose_cvt<<<dim3(512 / 32, 256 / 32),   tb, 0, stream>>>(d_in[15], wtF1, 256,  512,  FLAG);
  transpose_cvt<<<dim3(256 / 32, 512 / 32),   tb, 0, stream>>>(d_in[17], wtF2, 512,  256,  FLAG);

  input_mlp2<<<B_ * T_, 128, 0, stream>>>(d_in[0], d_in[1], d_in[2], d_in[3], d_in[4],
                                          FLAG, XG, d_out);
  gru_scan4<<<256, 256, 0, stream>>>(XG, d_in[5], d_in[6], d_in[7], d_in[8], FLAG, GRUO);

  // qk = gruo @ Wqk + b   (M=16384, N=2048, K=1024)
  gemm_bt<1, 0><<<dim3(128 * 16, 1), 256, 0, stream>>>(GRUO, 1024, 0, wtI, 1024, 0,
      QK, 2048, 0, 0, 1, BIASA, nullptr, 1024, 128, FLAG);
  // vt = (gruo @ Wv + b)^T per head  -> VT[z][d][s]
  gemm_bt<4, 0><<<dim3(128 * 8, 1), 256, 0, stream>>>(GRUO, 1024, 0, wtI + 2048 * 1024, 1024, 0,
      VT, 0, 0, 0, 1, BIASA + 2048, nullptr, 1024, 128, FLAG);
  // P = softmax(QK^T/16)
  attn_qk_softmax<<<dim3(T_ / 64, B_ * NH_), 256, 0, stream>>>(QK, Pbuf);
  // ctx = P @ V  (batched z=256)
  gemm_bt<0, 0><<<dim3(2 * 2, B_ * NH_), 256, 0, stream>>>(Pbuf, 256, 65536, VT, 256, 65536,
      CTX, 1024, (long)T_ * E_, 256, 4, nullptr, nullptr, 256, 2, FLAG);
  // mha = ctx @ mha_out_w + b
  gemm_bt<1, 0><<<dim3(128 * 8, 1), 256, 0, stream>>>(CTX, 1024, 0, wtM, 1024, 0,
      MHA, 1024, 0, 0, 1, BIASA + 3072, nullptr, 1024, 128, FLAG);
  // h1 = mha @ outp_w + b
  gemm_bt<1, 0><<<dim3(128 * 2, 1), 256, 0, stream>>>(MHA, 1024, 0, wtO, 1024, 0,
      H1, 256, 0, 0, 1, BIASA + 4096, nullptr, 1024, 128, FLAG);
  // ffh = gelu(h1 @ ffn_w1 + b)
  gemm_bt<2, 0><<<dim3(128 * 4, 1), 256, 0, stream>>>(H1, 256, 0, wtF1, 256, 0,
      FFH, 512, 0, 0, 1, BIASA + 4352, nullptr, 256, 128, FLAG);
  // y = h1 + ffh @ ffn_w2 + b  -> final output (flagged dtype)
  gemm_bt<3, 1><<<dim3(128 * 2, 1), 256, 0, stream>>>(FFH, 512, 0, wtF2, 512, 0,
      d_out, 256, 0, 0, 1, BIASA + 4864, H1, 512, 128, FLAG);
}

// Round 8
// 467.147 us; speedup vs baseline: 16.3033x; 1.1647x over previous
//
#include <hip/hip_runtime.h>
#include <hip/hip_bf16.h>
#include <math.h>

// Problem dims
#define B_  64
#define T_  256
#define F_  128
#define H_  8
#define E_  1024   // F*H
#define NH_ 4
#define HD_ 256    // E/NH
#define D_  256

// output element offsets within d_out (element units of the storage dtype)
#define OFF_Y_  0L
#define OFF_FI_ 4194304L
#define OFF_IA_ 4210688L

typedef unsigned short u16;
typedef unsigned int   u32;
typedef short bf16x8 __attribute__((ext_vector_type(8)));
typedef float f32x4  __attribute__((ext_vector_type(4)));

__device__ __forceinline__ float bf2f(u16 u) {
  union { u32 u; float f; } x; x.u = ((u32)u) << 16; return x.f;
}
__device__ __forceinline__ u16 f2bf(float f) {
  union { float f; u32 u; } x; x.f = f;
  u32 r = (x.u + 0x7fffu + ((x.u >> 16) & 1u)) >> 16;
  return (u16)r;
}
__device__ __forceinline__ float gelu_exact(float v) {
  return 0.5f * v * (1.f + erff(v * 0.70710678118654752f));
}
__device__ __forceinline__ float sigmoidf_(float v) {
  return 1.f / (1.f + __expf(-v));
}
__device__ __forceinline__ float ldv(const void* p, long i, bool isf) {
  return isf ? ((const float*)p)[i] : bf2f(((const u16*)p)[i]);
}
__device__ __forceinline__ void stv(void* p, long i, float v, bool isf) {
  if (isf) ((float*)p)[i] = v;
  else ((u16*)p)[i] = f2bf(v);
}
// async global->LDS, 16B/lane: LDS dest = wave-uniform base + lane*16 (HW)
__device__ __forceinline__ void gld16(void* lds, const void* g) {
  __builtin_amdgcn_global_load_lds(
      (const __attribute__((address_space(1))) u32*)g,
      (__attribute__((address_space(3))) u32*)lds, 16, 0, 0);
}

// ---------------------------------------------------------------------------
// dtype detector (flag: 0 = bf16 storage, 1 = f32 storage)
// ---------------------------------------------------------------------------
__global__ void detect_dtype(const u16* __restrict__ x, u32* __restrict__ flag) {
  if (threadIdx.x == 0 && blockIdx.x == 0) {
    int good = 0;
    for (int i = 0; i < 512; ++i) {
      u16 v = x[i];
      int e = (v >> 7) & 0xFF;
      if (v == 0 || (e >= 100 && e <= 140)) ++good;
    }
    *flag = (good >= 450) ? 0u : 1u;
  }
}

// convert a small raw tensor (f32 or bf16) to bf16
__global__ __launch_bounds__(256)
void convert_in(const void* __restrict__ src, u16* __restrict__ dst, int n,
                const u32* __restrict__ flag) {
  const bool isf = (*flag != 0);
  int i = blockIdx.x * 256 + threadIdx.x;
  if (i < n) dst[i] = isf ? f2bf(((const float*)src)[i]) : ((const u16*)src)[i];
}

// fused transpose + convert: out[c][r] (bf16) = in[r][c] (raw). dims %32 == 0
__global__ void transpose_cvt(const void* __restrict__ in, u16* __restrict__ out,
                              int R, int C, const u32* __restrict__ flag) {
  const bool isf = (*flag != 0);
  __shared__ float t[32][33];
  const int c0 = blockIdx.x * 32, r0 = blockIdx.y * 32;
  const int tx = threadIdx.x, ty = threadIdx.y;
  for (int i = ty; i < 32; i += 8)
    t[i][tx] = ldv(in, (long)(r0 + i) * C + c0 + tx, isf);
  __syncthreads();
  for (int i = ty; i < 32; i += 8)
    out[(long)(c0 + i) * R + r0 + tx] = f2bf(t[tx][i]);
}

// ---------------------------------------------------------------------------
// K1: input-attention MLP (unchanged, passing)
// ---------------------------------------------------------------------------
__global__ __launch_bounds__(128)
void input_mlp2(const void* __restrict__ x,
                const void* __restrict__ w1, const void* __restrict__ b1,
                const void* __restrict__ w2, const void* __restrict__ b2,
                const u32* __restrict__ flag,
                u16* __restrict__ xg, void* __restrict__ dout) {
  const bool isf = (*flag != 0);
  const long row = blockIdx.x;
  const int tid = threadIdx.x;
  __shared__ float xr[F_];
  __shared__ float hid[32];
  __shared__ float red[2];
  float xv = ldv(x, row * F_ + tid, isf);
  xr[tid] = xv;
  __syncthreads();
  if (tid < 32) {
    float s = ldv(b1, tid, isf);
    for (int f = 0; f < F_; ++f) s += xr[f] * ldv(w1, f * 32 + tid, isf);
    hid[tid] = gelu_exact(s);
  }
  __syncthreads();
  float s = ldv(b2, tid, isf);
  #pragma unroll 8
  for (int j = 0; j < 32; ++j) s += hid[j] * ldv(w2, j * F_ + tid, isf);
  float ia = sigmoidf_(s);
  stv(dout, OFF_IA_ + row * F_ + tid, ia, isf);
  xg[row * F_ + tid] = f2bf(ia * xv);
  float v = ia;
  for (int o = 32; o > 0; o >>= 1) v += __shfl_down(v, o);
  if ((tid & 63) == 0) red[tid >> 6] = v;
  __syncthreads();
  if (tid == 0) stv(dout, OFF_FI_ + row, red[0] + red[1], isf);
}

// ---------------------------------------------------------------------------
// K2 v4: GRU bank (unchanged, passing): 8 lanes per recurrence, LDS h-exchange
// ---------------------------------------------------------------------------
__global__ __launch_bounds__(256)
void gru_scan4(const u16* __restrict__ xg, const void* __restrict__ W_ih,
               const void* __restrict__ W_hh, const void* __restrict__ b_ih,
               const void* __restrict__ b_hh, const u32* __restrict__ flag,
               u16* __restrict__ gruo) {
  const bool isf = (*flag != 0);
  const int tid = threadIdx.x;
  const int ric = tid >> 3;
  const int j   = tid & 7;
  const int rec = blockIdx.x * 32 + ric;
  const int b = rec >> 7, f = rec & 127;
  __shared__ __align__(16) float hbuf[32][8];
  float whr[8], whz[8], whn[8];
  #pragma unroll
  for (int k = 0; k < 8; ++k) {
    whr[k] = ldv(W_hh, (long)f * 192 + j * 8 + k, isf);
    whz[k] = ldv(W_hh, (long)f * 192 + (8 + j) * 8 + k, isf);
    whn[k] = ldv(W_hh, (long)f * 192 + (16 + j) * 8 + k, isf);
  }
  const float wir = ldv(W_ih, f * 24 + j, isf);
  const float wiz = ldv(W_ih, f * 24 + 8 + j, isf);
  const float win = ldv(W_ih, f * 24 + 16 + j, isf);
  const float cbr = ldv(b_ih, f * 24 + j, isf) + ldv(b_hh, f * 24 + j, isf);
  const float cbz = ldv(b_ih, f * 24 + 8 + j, isf) + ldv(b_hh, f * 24 + 8 + j, isf);
  const float bin_ = ldv(b_ih, f * 24 + 16 + j, isf);
  const float bhn_ = ldv(b_hh, f * 24 + 16 + j, isf);
  float h[8];
  #pragma unroll
  for (int k = 0; k < 8; ++k) h[k] = 0.f;
  const u16* xp = xg + (long)b * T_ * F_ + f;
  u16* op = gruo + (long)b * T_ * E_ + f * 8 + j;
  float xv = bf2f(xp[0]);
  for (int t = 0; t < T_; ++t) {
    float xn = (t + 1 < T_) ? bf2f(xp[(t + 1) * F_]) : 0.f;
    float ar = fmaf(xv, wir, cbr);
    float az = fmaf(xv, wiz, cbz);
    float an = bhn_;
    #pragma unroll
    for (int k = 0; k < 8; ++k) {
      ar = fmaf(h[k], whr[k], ar);
      az = fmaf(h[k], whz[k], az);
      an = fmaf(h[k], whn[k], an);
    }
    const float r = sigmoidf_(ar);
    const float z = sigmoidf_(az);
    const float a = fmaf(r, an, fmaf(xv, win, bin_));
    const float e = __expf(2.f * a);
    const float n = 1.f - 2.f / (e + 1.f);
    const float hn = fmaf(z, h[j] - n, n);
    op[(long)t * E_] = f2bf(hn);
    hbuf[ric][j] = hn;
    f32x4 h0 = *(const f32x4*)&hbuf[ric][0];
    f32x4 h1 = *(const f32x4*)&hbuf[ric][4];
    h[0] = h0[0]; h[1] = h0[1]; h[2] = h0[2]; h[3] = h0[3];
    h[4] = h1[0]; h[5] = h1[1]; h[6] = h1[2]; h[7] = h1[3];
    xv = xn;
  }
}

// ---------------------------------------------------------------------------
// bt-form MFMA GEMM v2: BK=64, XOR-swizzled staging (rule #21: linear LDS dest,
// chunk-permuted global SOURCE, un-permuted read) -> conflict-free ds_read_b128.
// C[m][n] = sum_k A[m][k]*B[n][k]. 128x128 tile, 4 waves (2x2).
// EPI: 0=none, 1=+bias, 2=+bias+gelu, 3=+bias+resid. COUT: dtype-flagged y.
// ---------------------------------------------------------------------------
template <int EPI, int COUT>
__global__ __launch_bounds__(256)
void gemm_bt(const u16* __restrict__ A, int lda,
             const u16* __restrict__ Bp, int ldb,
             void* __restrict__ Cg, int ldc,
             const u16* __restrict__ bias, const u16* __restrict__ resid,
             int K, int nbm, const u32* __restrict__ flag) {
  const bool isf = (*flag != 0);
  const int bm = blockIdx.x % nbm, bn = blockIdx.x / nbm;
  const int w = threadIdx.x >> 6, lane = threadIdx.x & 63;
  __shared__ __align__(16) u16 As[128 * 64];   // 16 KB
  __shared__ __align__(16) u16 Bs[128 * 64];   // 16 KB
  const long m0 = (long)bm * 128, n0 = (long)bn * 128;
  const int wm = w >> 1, wn = w & 1;
  // staging: lane -> row lr8 = lane>>3 (8 rows/gld16), chunk (lane&7) of 8 elems,
  // source chunk permuted by row&7 so swizzled layout lands via linear dest.
  const int lr8 = lane >> 3;
  const int csw = ((lane & 7) ^ (lr8 & 7)) * 8;
  f32x4 acc[4][4] = {};
  const int nk = K >> 6;
  const int lr = lane & 15, lq = lane >> 4;   // frag row / k-quarter
  for (int kt = 0; kt < nk; ++kt) {
    const int k0 = kt << 6;
    __syncthreads();
    #pragma unroll
    for (int c = 0; c < 4; ++c) {
      const int rb = w * 32 + c * 8;          // 8-row chunk staged per gld16
      gld16((char*)As + rb * 128, A + (m0 + rb + lr8) * (long)lda + k0 + csw);
      gld16((char*)Bs + rb * 128, Bp + (n0 + rb + lr8) * (long)ldb + k0 + csw);
    }
    __syncthreads();
    #pragma unroll
    for (int sub = 0; sub < 2; ++sub) {
      const int ch = sub * 4 + lq;            // global k-chunk 0..7
      const int co = ((ch ^ (lr & 7)) << 3);  // un-swizzle
      bf16x8 af[4], bfv[4];
      #pragma unroll
      for (int i = 0; i < 4; ++i)
        af[i] = *(const bf16x8*)&As[(wm * 64 + i * 16 + lr) * 64 + co];
      #pragma unroll
      for (int i = 0; i < 4; ++i)
        bfv[i] = *(const bf16x8*)&Bs[(wn * 64 + i * 16 + lr) * 64 + co];
      #pragma unroll
      for (int i = 0; i < 4; ++i) {
        #pragma unroll
        for (int j = 0; j < 4; ++j)
          acc[i][j] = __builtin_amdgcn_mfma_f32_16x16x32_bf16(af[i], bfv[j], acc[i][j], 0, 0, 0);
      }
    }
  }
  const int rq = lq * 4;
  #pragma unroll
  for (int j = 0; j < 4; ++j) {
    const long col = n0 + wn * 64 + j * 16 + lr;
    const float bv = (EPI >= 1) ? bf2f(bias[col]) : 0.f;
    #pragma unroll
    for (int i = 0; i < 4; ++i) {
      const long row0 = m0 + wm * 64 + i * 16 + rq;
      #pragma unroll
      for (int q = 0; q < 4; ++q) {
        const long row = row0 + q;
        float v = acc[i][j][q] + bv;
        if (EPI == 2) v = gelu_exact(v);
        if (EPI == 3) v += bf2f(resid[row * (long)ldc + col]);
        if (COUT) stv(Cg, row * (long)ldc + col, v, isf);
        else ((u16*)Cg)[row * (long)ldc + col] = f2bf(v);
      }
    }
  }
}

// ---------------------------------------------------------------------------
// Fused attention: per block (qt, z=b*4+h): 64 q-rows.
// Phase 1: S = QK^T/16 via MFMA (gld16-staged Q,K from QKV [B,T,3E]) + softmax
//          -> P into padded LDS [64][264].
// Phase 2: per 32-s tile: gld16 V rows -> LDS Ts[32][256]; transpose to
//          Vt[256][40] (conflict-free b128 writes); MFMA P@V -> ctx.
// ---------------------------------------------------------------------------
__global__ __launch_bounds__(256)
void attn_fused(const u16* __restrict__ qkv, u16* __restrict__ ctx) {
  const int z = blockIdx.y, bb = z >> 2, hh = z & 3;
  const int w = threadIdx.x >> 6, lane = threadIdx.x & 63;
  const int tid = threadIdx.x;
  const long t0 = (long)blockIdx.x * 64;
  __shared__ __align__(16) u16 P1[10240];   // Qs[0..2047]+Ks[2048..] / Ts in ph2
  __shared__ __align__(16) u16 Pl[64 * 264];
  __shared__ __align__(16) u16 Vt[256 * 40];
  const u16* qb = qkv + (long)bb * T_ * 3 * E_ + hh * HD_;
  const u16* kb = qb + E_;
  const u16* vb = qb + 2 * E_;
  const int rr = lane >> 2, cc = lane & 3;
  const int lr = lane & 15, lq = lane >> 4, lk = lq * 8;
  // ---- phase 1: QK^T ----
  f32x4 acc[16] = {};
  for (int kt = 0; kt < 8; ++kt) {
    const int k0 = kt * 32;
    __syncthreads();
    gld16((char*)P1 + w * 16 * 64, qb + (t0 + w * 16 + rr) * (3L * E_) + k0 + cc * 8);
    #pragma unroll
    for (int c = 0; c < 4; ++c) {
      const int rb = w * 64 + c * 16;
      gld16((char*)P1 + 4096 + rb * 64, kb + (long)(rb + rr) * (3L * E_) + k0 + cc * 8);
    }
    __syncthreads();
    bf16x8 aq = *(const bf16x8*)&P1[(w * 16 + lr) * 32 + lk];
    #pragma unroll
    for (int nt = 0; nt < 16; ++nt) {
      bf16x8 bk = *(const bf16x8*)&P1[2048 + (nt * 16 + lr) * 32 + lk];
      acc[nt] = __builtin_amdgcn_mfma_f32_16x16x32_bf16(aq, bk, acc[nt], 0, 0, 0);
    }
  }
  // ---- softmax -> Pl ----
  #pragma unroll
  for (int q = 0; q < 4; ++q) {
    float mx = -3.4e38f;
    #pragma unroll
    for (int nt = 0; nt < 16; ++nt) mx = fmaxf(mx, acc[nt][q]);
    mx = fmaxf(mx, __shfl_xor(mx, 1));
    mx = fmaxf(mx, __shfl_xor(mx, 2));
    mx = fmaxf(mx, __shfl_xor(mx, 4));
    mx = fmaxf(mx, __shfl_xor(mx, 8));
    float e[16], sum = 0.f;
    #pragma unroll
    for (int nt = 0; nt < 16; ++nt) {
      e[nt] = __expf((acc[nt][q] - mx) * 0.0625f);
      sum += e[nt];
    }
    sum += __shfl_xor(sum, 1);
    sum += __shfl_xor(sum, 2);
    sum += __shfl_xor(sum, 4);
    sum += __shfl_xor(sum, 8);
    const float inv = 1.f / sum;
    const int rowl = w * 16 + lq * 4 + q;
    #pragma unroll
    for (int nt = 0; nt < 16; ++nt)
      Pl[rowl * 264 + nt * 16 + lr] = f2bf(e[nt] * inv);
  }
  // ---- phase 2: ctx = P @ V ----
  f32x4 acc2[16] = {};
  for (int st = 0; st < 8; ++st) {
    const int s0 = st * 32;
    __syncthreads();   // Ts/Vt free (prev tile's reads done)
    // stage V rows s0..s0+31 into Ts = P1[0..8191] ([32][256] linear)
    #pragma unroll
    for (int c = 0; c < 4; ++c) {
      const int rb = w * 8 + c * 2;   // 2 rows per gld16
      gld16((char*)P1 + rb * 512, vb + (s0 + rb + (lane >> 5)) * (3L * E_) + (lane & 31) * 8);
    }
    __syncthreads();   // drains vmcnt (compiler emits full waitcnt at barrier)
    // transpose: thread t owns d-row t of Vt
    u16 col[32];
    #pragma unroll
    for (int si = 0; si < 32; ++si) col[si] = P1[si * 256 + tid];
    #pragma unroll
    for (int cq = 0; cq < 4; ++cq)
      *(uint4*)&Vt[tid * 40 + cq * 8] = *(const uint4*)&col[cq * 8];
    __syncthreads();
    // MFMA: pa = P[w-rows][s-tile], bv = Vt rows (d), k = s
    bf16x8 pa = *(const bf16x8*)&Pl[(w * 16 + lr) * 264 + s0 + lk];
    #pragma unroll
    for (int nt = 0; nt < 16; ++nt) {
      bf16x8 bv = *(const bf16x8*)&Vt[(nt * 16 + lr) * 40 + lk];
      acc2[nt] = __builtin_amdgcn_mfma_f32_16x16x32_bf16(pa, bv, acc2[nt], 0, 0, 0);
    }
  }
  // ---- epilogue ----
  const int rq = lq * 4;
  #pragma unroll
  for (int nt = 0; nt < 16; ++nt) {
    const int col = nt * 16 + lr;
    #pragma unroll
    for (int q = 0; q < 4; ++q) {
      const long row = t0 + w * 16 + rq + q;
      ctx[((long)bb * T_ + row) * E_ + hh * HD_ + col] = f2bf(acc2[nt][q]);
    }
  }
}

// ---------------------------------------------------------------------------
extern "C" void kernel_launch(void* const* d_in, const int* in_sizes, int n_in,
                              void* d_out, int out_size, void* d_ws, size_t ws_size,
                              hipStream_t stream) {
  (void)in_sizes; (void)n_in; (void)out_size; (void)ws_size;
  char* ws = (char*)d_ws;
  // ws layout (bytes), peak 151MB (proven safe: round 2 wrote 165.7MB cleanly)
  u16* BIASA = (u16*)(ws + 0);          // bf16 biases: ipb@0(3072) mhb@3072 opb@4096 fb1@4352 fb2@4864
  u32* FLAG  = (u32*)(ws + 12288);
  u16* wtI   = (u16*)(ws + 65536);      // [3072][1024] 6.29MB
  u16* wtM   = (u16*)(ws + 6356992);    // [1024][1024] 2.10MB
  u16* wtO   = (u16*)(ws + 8454144);    // [256][1024]  0.52MB
  u16* wtF1  = (u16*)(ws + 8978432);    // [512][256]
  u16* wtF2  = (u16*)(ws + 9240576);    // [256][512]   -> ends 9502720
  u16* XG    = (u16*)(ws + 9502720);    // [B,T,F] 4.19MB
  u16* GRUO  = (u16*)(ws + 16777216);   // [B,T,E] 33.55MB (dead after QKV gemm)
  u16* CTX   = GRUO;                    // [B,T,E] overlay
  u16* QKV   = (u16*)(ws + 50331648);   // [B,T,3E] 100.7MB -> ends 150994944 (dead after attn)
  u16* MHA   = (u16*)(ws + 50331648);   // [B,T,E] overlay on dead QKV
  u16* H1    = (u16*)(ws + 83886080);   // [B,T,D] 8.39MB
  u16* FFH   = (u16*)(ws + 92274688);   // [B,T,2D] 16.78MB -> ends 109051904

  detect_dtype<<<1, 64, 0, stream>>>((const u16*)d_in[0], FLAG);

  // biases -> bf16 arena
  convert_in<<<12, 256, 0, stream>>>(d_in[10], BIASA + 0,    3072, FLAG);
  convert_in<<<4,  256, 0, stream>>>(d_in[12], BIASA + 3072, 1024, FLAG);
  convert_in<<<1,  256, 0, stream>>>(d_in[14], BIASA + 4096, 256,  FLAG);
  convert_in<<<2,  256, 0, stream>>>(d_in[16], BIASA + 4352, 512,  FLAG);
  convert_in<<<1,  256, 0, stream>>>(d_in[18], BIASA + 4864, 256,  FLAG);

  dim3 tb(32, 8);
  transpose_cvt<<<dim3(3072 / 32, 1024 / 32), tb, 0, stream>>>(d_in[9],  wtI,  1024, 3072, FLAG);
  transpose_cvt<<<dim3(1024 / 32, 1024 / 32), tb, 0, stream>>>(d_in[11], wtM,  1024, 1024, FLAG);
  transpose_cvt<<<dim3(256 / 32, 1024 / 32),  tb, 0, stream>>>(d_in[13], wtO,  1024, 256,  FLAG);
  transpose_cvt<<<dim3(512 / 32, 256 / 32),   tb, 0, stream>>>(d_in[15], wtF1, 256,  512,  FLAG);
  transpose_cvt<<<dim3(256 / 32, 512 / 32),   tb, 0, stream>>>(d_in[17], wtF2, 512,  256,  FLAG);

  input_mlp2<<<B_ * T_, 128, 0, stream>>>(d_in[0], d_in[1], d_in[2], d_in[3], d_in[4],
                                          FLAG, XG, d_out);
  gru_scan4<<<256, 256, 0, stream>>>(XG, d_in[5], d_in[6], d_in[7], d_in[8], FLAG, GRUO);

  // qkv = gruo @ in_proj + b   (M=16384, N=3072, K=1024)
  gemm_bt<1, 0><<<dim3(128 * 24, 1), 256, 0, stream>>>(GRUO, 1024, wtI, 1024,
      QKV, 3072, BIASA, nullptr, 1024, 128, FLAG);
  // fused attention -> CTX [B,T,E]
  attn_fused<<<dim3(4, B_ * NH_), 256, 0, stream>>>(QKV, CTX);
  // mha = ctx @ mha_out_w + b  (M=16384, N=1024, K=1024)
  gemm_bt<1, 0><<<dim3(128 * 8, 1), 256, 0, stream>>>(CTX, 1024, wtM, 1024,
      MHA, 1024, BIASA + 3072, nullptr, 1024, 128, FLAG);
  // h1 = mha @ outp_w + b  (M=16384, N=256, K=1024)
  gemm_bt<1, 0><<<dim3(128 * 2, 1), 256, 0, stream>>>(MHA, 1024, wtO, 1024,
      H1, 256, BIASA + 4096, nullptr, 1024, 128, FLAG);
  // ffh = gelu(h1 @ ffn_w1 + b)  (M=16384, N=512, K=256)
  gemm_bt<2, 0><<<dim3(128 * 4, 1), 256, 0, stream>>>(H1, 256, wtF1, 256,
      FFH, 512, BIASA + 4352, nullptr, 256, 128, FLAG);
  // y = h1 + ffh @ ffn_w2 + b  (M=16384, N=256, K=512) -> final output
  gemm_bt<3, 1><<<dim3(128 * 2, 1), 256, 0, stream>>>(FFH, 512, wtF2, 512,
      d_out, 256, BIASA + 4864, H1, 512, 128, FLAG);
}